// Round 1
// baseline (8402.138 us; speedup 1.0000x reference)
//
#include <hip/hip_runtime.h>
#include <cstddef>

#define NNODES 10000
#define NEDGES 256000
#define NGRAPH 32
#define NELEM  10
#define FF     64
#define LL     9
#define NBB    8
#define HIDN   16
#define RMAXF  5.0f
#define INV_AVG 0.0390625f   /* 1/25.6 exact */
#define PI_F   3.14159265358979f

// ---------------- workspace layout (float elements) ----------------
// total 32,926,002 floats = ~131.7 MB
constexpr size_t O_H0   = 0;          // 640000
constexpr size_t O_S1   = 640000;     // 640000
constexpr size_t O_AGG1 = 1280000;    // 5760000 (fwd agg1; reused as d_agg2 in bwd)
constexpr size_t O_AGG2 = 7040000;    // 5760000 (fwd agg2; reused as d_agg1 in bwd)
constexpr size_t O_F1   = 12800000;   // 5760000 feats1
constexpr size_t O_F2   = 18560000;   // 5760000 feats2
constexpr size_t O_C1   = 24320000;   // 640000
constexpr size_t O_C2   = 24960000;   // 640000
constexpr size_t O_DS1  = 25600000;   // 640000
constexpr size_t O_CSH  = 26240000;   // 2304000 compact sh
constexpr size_t O_CEF  = 28544000;   // 2048000 compact ef
constexpr size_t O_CR   = 30592000;   // 256000
constexpr size_t O_CVEC = 30848000;   // 768000
constexpr size_t O_DVEC = 31616000;   // 768000
constexpr size_t O_DPOS = 32384000;   // 30000
constexpr size_t O_CSND = 32414000;   // 256000 (int)
constexpr size_t O_CRCV = 32670000;   // 256000 (int)
constexpr size_t O_CNT  = 32926000;   // 2 (int): [0]=count, [1]=count rounded to 32

__device__ __forceinline__ float siluf(float z){
  return z*(1.f/(1.f+__expf(-z)));
}
// butterfly reduce across 64 lanes; all lanes get the sum
__device__ __forceinline__ float wred(float v){
#pragma unroll
  for(int o=32;o>0;o>>=1) v += __shfl_xor(v,o,64);
  return v;
}

// ---------------- node embedding + e0 ----------------
__global__ __launch_bounds__(256) void k_embed(
    const float* __restrict__ attrs, const float* __restrict__ Wemb,
    const float* __restrict__ ae, const int* __restrict__ batch,
    float* __restrict__ h0, float* __restrict__ totE, float* __restrict__ nodeE){
  int t = blockIdx.x*256 + threadIdx.x;
  int n = t >> 6, f = t & 63;
  float acc = 0.f;
#pragma unroll
  for(int k=0;k<NELEM;k++) acc += attrs[n*NELEM+k]*Wemb[k*FF+f];
  h0[(size_t)n*FF+f] = acc;
  if(f==0){
    float e0 = 0.f;
#pragma unroll
    for(int k=0;k<NELEM;k++) e0 += attrs[n*NELEM+k]*ae[k];
    nodeE[n] = e0;
    atomicAdd(&totE[batch[n]], e0);
  }
}

// ---------------- edge geometry + compaction (r < RMAX only) ----------------
__global__ __launch_bounds__(256) void k_geom(
    const float* __restrict__ pos, const float* __restrict__ shifts, const int* __restrict__ eidx,
    float* __restrict__ csh, float* __restrict__ cef, float* __restrict__ cr,
    float* __restrict__ cvec, int* __restrict__ csnd, int* __restrict__ crcv, int* __restrict__ cnt){
  int e = blockIdx.x*256 + threadIdx.x;
  int sn = eidx[e], rc = eidx[NEDGES + e];
  float vx = pos[rc*3+0]-pos[sn*3+0]+shifts[(size_t)e*3+0];
  float vy = pos[rc*3+1]-pos[sn*3+1]+shifts[(size_t)e*3+1];
  float vz = pos[rc*3+2]-pos[sn*3+2]+shifts[(size_t)e*3+2];
  float r = sqrtf(vx*vx+vy*vy+vz*vz+1e-12f);
  if(r >= RMAXF) return;  // env=0 edge: zero message AND zero gradient -> drop
  int i = atomicAdd(cnt, 1);
  csnd[i]=sn; crcv[i]=rc; cr[i]=r;
  cvec[(size_t)i*3+0]=vx; cvec[(size_t)i*3+1]=vy; cvec[(size_t)i*3+2]=vz;
  float inv = 1.f/r, x=vx*inv, y=vy*inv, z=vz*inv;
  const float s3=1.7320508f, s5=2.23606798f, s15=3.87298335f;
  float* sh = csh + (size_t)i*LL;
  sh[0]=1.f; sh[1]=s3*x; sh[2]=s3*y; sh[3]=s3*z; sh[4]=s15*x*y; sh[5]=s15*y*z;
  sh[6]=0.5f*s5*(3.f*z*z-1.f); sh[7]=s15*x*z; sh[8]=0.5f*s15*(x*x-y*y);
  float xr = r*(1.f/RMAXF);
  float x2=xr*xr, x4=x2*x2, x6=x4*x2, x7=x6*xr, x8=x7*xr;
  float env = 1.f - 28.f*x6 + 48.f*x7 - 21.f*x8;   // p=6 polynomial cutoff
  const float CB = 0.632455532f;                    // sqrt(2/RMAX)
#pragma unroll
  for(int b=0;b<NBB;b++){
    float a = (b+1)*(PI_F/RMAXF);
    cef[(size_t)i*NBB+b] = CB*sinf(a*r)*inv*env;
  }
}

// pad compact list to multiple of 32 with harmless zero edges
__global__ void k_pad(float* csh, float* cef, float* cr, float* cvec,
                      int* csnd, int* crcv, int* cnt){
  int n = cnt[0];
  int nr = (n+31)&~31;
  int i = n + threadIdx.x;
  if(i < nr){
    csnd[i]=0; crcv[i]=0; cr[i]=1.f;
    cvec[(size_t)i*3+0]=0.f; cvec[(size_t)i*3+1]=0.f; cvec[(size_t)i*3+2]=1.f;
    for(int l=0;l<LL;l++) csh[(size_t)i*LL+l]=0.f;
    for(int b=0;b<NBB;b++) cef[(size_t)i*NBB+b]=0.f;
  }
  if(threadIdx.x==0) cnt[1]=nr;
}

// ---------------- fused edge forward: MLP -> tw -> message scatter ----------------
// 32 edges/block, 8 per wave. LDS ~63.4 KB.
__global__ __launch_bounds__(256,2) void k_edge_fwd(
    const float* __restrict__ csh, const float* __restrict__ cef,
    const int* __restrict__ csnd, const int* __restrict__ crcv, const int* __restrict__ cnt,
    const float* __restrict__ src,
    const float* __restrict__ W1, const float* __restrict__ W2,
    const float* __restrict__ W3, const float* __restrict__ W4,
    float* __restrict__ agg){
  if(blockIdx.x*32 >= cnt[1]) return;
  __shared__ float W1s[NBB*FF];
  __shared__ float W2s[FF*65], W3s[FF*65];  // padded: conflict-free both orientations
  __shared__ float hA[32*FF], hB[32*FF];
  __shared__ float shs[32*LL], efs[32*NBB];
  __shared__ int   sndS[32], rcvS[32];
  __shared__ float W4c[4*576];
  const int t = threadIdx.x;
  const size_t e0 = (size_t)blockIdx.x*32;
  for(int i=t;i<NBB*FF;i+=256) W1s[i]=W1[i];
  for(int i=t;i<FF*FF;i+=256){ int j=i>>6, c=i&63; W2s[j*65+c]=W2[i]; W3s[j*65+c]=W3[i]; }
  for(int i=t;i<32*LL;i+=256) shs[i]=csh[e0*LL+i];
  for(int i=t;i<32*NBB;i+=256) efs[i]=cef[e0*NBB+i];
  if(t<32){ sndS[t]=csnd[e0+t]; rcvS[t]=crcv[e0+t]; }
  __syncthreads();
  const int w=t>>6, f=t&63;
  // L1: ef(8) -> h1(64)
#pragma unroll
  for(int i=0;i<8;i++){
    int e=w*8+i; float z=0.f;
#pragma unroll
    for(int b=0;b<NBB;b++) z += efs[e*NBB+b]*W1s[b*FF+f];
    hA[e*FF+f]=siluf(z);
  }
  __syncthreads();
  // L2
#pragma unroll
  for(int i=0;i<8;i++){
    int e=w*8+i; float z=0.f;
#pragma unroll
    for(int j=0;j<FF;j++) z += hA[e*FF+j]*W2s[j*65+f];
    hB[e*FF+f]=siluf(z);
  }
  __syncthreads();
  // L3 (write back into hA = h3)
#pragma unroll
  for(int i=0;i<8;i++){
    int e=w*8+i; float z=0.f;
#pragma unroll
    for(int j=0;j<FF;j++) z += hB[e*FF+j]*W3s[j*65+f];
    hA[e*FF+f]=siluf(z);
  }
  __syncthreads();
  // L4: tw[f][l] = sum_j h3[j]*W4[j, f*9+l], W4 streamed in 4-row chunks
  float tw[8][9];
#pragma unroll
  for(int i=0;i<8;i++)
#pragma unroll
    for(int l=0;l<LL;l++) tw[i][l]=0.f;
  for(int jc=0;jc<16;jc++){
    for(int i=t;i<4*576;i+=256) W4c[i]=W4[jc*(4*576)+i];
    __syncthreads();
#pragma unroll
    for(int j4=0;j4<4;j4++){
      int j=jc*4+j4;
      float wv[9];
#pragma unroll
      for(int l=0;l<LL;l++) wv[l]=W4c[j4*576 + f*LL + l];
#pragma unroll
      for(int i=0;i<8;i++){
        float h3 = hA[(w*8+i)*FF + j];
#pragma unroll
        for(int l=0;l<LL;l++) tw[i][l] += h3*wv[l];
      }
    }
    __syncthreads();
  }
  // epilogue: msg = src[snd,f]*sh[l]*tw/AVG  -> atomic scatter to agg[rcv]
#pragma unroll
  for(int i=0;i<8;i++){
    int e=w*8+i;
    int sn=sndS[e], rc=rcvS[e];
    float sv = src[(size_t)sn*FF+f];
    float* ap = agg + ((size_t)rc*FF + f)*LL;
#pragma unroll
    for(int l=0;l<LL;l++) atomicAdd(&ap[l], sv*shs[e*LL+l]*tw[i][l]*INV_AVG);
  }
}

// ---------------- node forward: feats, inv, c, h, energies ----------------
template<int LAYER>
__global__ __launch_bounds__(256,2) void k_node_fwd(
    const float* __restrict__ agg, const float* __restrict__ src,
    const int* __restrict__ batch,
    const float* __restrict__ Wlin, const float* __restrict__ Wsc,
    const float* __restrict__ Wpr,
    const float* __restrict__ wread,
    const float* __restrict__ Wr1, const float* __restrict__ wr2,
    float* __restrict__ feats, float* __restrict__ cbuf,
    float* __restrict__ s1out,
    float* __restrict__ nfeats, float* __restrict__ nodeE, float* __restrict__ totE){
  __shared__ float Wl[FF*65], Wscs[FF*65], Wprs[FF*65];
  __shared__ float Wr1s[FF*HIDN];
  __shared__ float av[4*FF], invS[4*FF];
  const int t=threadIdx.x, w=t>>6, g=t&63;
  const int n = blockIdx.x*4 + w;
  for(int i=t;i<FF*FF;i+=256){ int a=i>>6,b=i&63; Wscs[a*65+b]=Wsc[i]; Wprs[a*65+b]=Wpr[i]; }
  if(LAYER==2) for(int i=t;i<FF*HIDN;i+=256) Wr1s[i]=Wr1[i];
  float fr[9];
#pragma unroll
  for(int l=0;l<LL;l++){
    __syncthreads();
    for(int i=t;i<FF*FF;i+=256){ int a=i>>6,b=i&63; Wl[a*65+b]=Wlin[(size_t)l*FF*FF+i]; }
    av[t] = agg[((size_t)n*FF + g)*LL + l];   // node w, feature g
    __syncthreads();
    float acc=0.f;
#pragma unroll
    for(int ff=0;ff<FF;ff++) acc += av[w*FF+ff]*Wl[ff*65+g];
    fr[l]=acc;
  }
  __syncthreads();
  av[t] = src[(size_t)n*FF + g];
  __syncthreads();
  float sacc=0.f;
#pragma unroll
  for(int ff=0;ff<FF;ff++) sacc += av[w*FF+ff]*Wscs[ff*65+g];
  fr[0]+=sacc;
  float* fp = feats + ((size_t)n*FF+g)*LL;
  float iv=0.f;
#pragma unroll
  for(int l=0;l<LL;l++){ fp[l]=fr[l]; iv+=fr[l]*fr[l]; }
  invS[t]=iv;
  __syncthreads();
  float c=1.f;
#pragma unroll
  for(int gg=0;gg<FF;gg++) c += invS[w*FF+gg]*Wprs[gg*65+g];
  cbuf[(size_t)n*FF+g]=c;
  float s0 = fr[0]*c;
  float* nf = nfeats + (size_t)n*(2*FF*LL) + (LAYER==2 ? FF*LL : 0) + g*LL;
#pragma unroll
  for(int l=0;l<LL;l++) nf[l]=fr[l]*c;
  if(LAYER==1) s1out[(size_t)n*FF+g]=s0;
  float epart;
  if(LAYER==1){
    epart = s0*wread[g];
  } else {
    __syncthreads();
    invS[t]=s0;           // reuse as s2 row
    __syncthreads();
    epart=0.f;
    if(g<HIDN){
      float tt=0.f;
#pragma unroll
      for(int gg=0;gg<FF;gg++) tt += invS[w*FF+gg]*Wr1s[gg*HIDN+g];
      epart = siluf(tt)*wr2[g];
    }
  }
  float esum = wred(epart);
  if(g==0){
    nodeE[n] += esum;
    atomicAdd(&totE[batch[n]], esum);
  }
}

// ---------------- node backward: d_agg, d_s1(sc-path) ----------------
template<int LAYER>
__global__ __launch_bounds__(256,2) void k_node_bwd(
    const float* __restrict__ feats, const float* __restrict__ cbuf,
    const float* __restrict__ Wlin, const float* __restrict__ Wpr,
    const float* __restrict__ Wsc,
    const float* __restrict__ Wr1, const float* __restrict__ wr2,
    const float* __restrict__ wread, const float* __restrict__ ds1in,
    const float* __restrict__ nfeats,
    float* __restrict__ dagg, float* __restrict__ ds1out){
  __shared__ float Wl[FF*65], Wprs[FF*65], Wscs[FF*65];
  __shared__ float Wr1s[FF*HIDN];
  __shared__ float dfS[4*FF*LL];
  __shared__ float rowS[4*FF];   // s2 row, then dc
  __shared__ float dtS[4*HIDN];
  const int t=threadIdx.x, w=t>>6, g=t&63;
  const int n = blockIdx.x*4 + w;
  for(int i=t;i<FF*FF;i+=256){ int a=i>>6,b=i&63; Wprs[a*65+b]=Wpr[i]; }
  if(LAYER==2){
    for(int i=t;i<FF*FF;i+=256){ int a=i>>6,b=i&63; Wscs[a*65+b]=Wsc[i]; }
    for(int i=t;i<FF*HIDN;i+=256) Wr1s[i]=Wr1[i];
  }
  __syncthreads();
  float dh0;
  if(LAYER==2){
    rowS[t] = nfeats[(size_t)n*(2*FF*LL) + FF*LL + g*LL + 0];  // s2 = h2[:,g,0]
    __syncthreads();
    if(g<HIDN){
      float tt=0.f;
#pragma unroll
      for(int gg=0;gg<FF;gg++) tt += rowS[w*FF+gg]*Wr1s[gg*HIDN+g];
      float sg = 1.f/(1.f+__expf(-tt));
      dtS[w*HIDN+g] = sg*(1.f + tt*(1.f-sg)) * wr2[g];  // silu'(t)*wr2
    }
    __syncthreads();
    dh0=0.f;
#pragma unroll
    for(int h=0;h<HIDN;h++) dh0 += dtS[w*HIDN+h]*Wr1s[g*HIDN+h];
  } else {
    dh0 = wread[g] + ds1in[(size_t)n*FF+g];
  }
  const float* fp = feats + ((size_t)n*FF+g)*LL;
  float f0 = fp[0];
  __syncthreads();
  rowS[t] = dh0*f0;     // dc[g]
  __syncthreads();
  float dinv=0.f;
#pragma unroll
  for(int gg=0;gg<FF;gg++) dinv += rowS[w*FF+gg]*Wprs[g*65+gg];  // d_inv[g']=sum dc[g]*Wpr[g'][g]
  float c = cbuf[(size_t)n*FF+g];
  float df[9];
#pragma unroll
  for(int l=0;l<LL;l++) df[l] = 2.f*dinv*fp[l];
  df[0] += dh0*c;
#pragma unroll
  for(int l=0;l<LL;l++) dfS[w*FF*LL + g*LL + l] = df[l];
  __syncthreads();
  if(LAYER==2){
    float ds=0.f;
#pragma unroll
    for(int gg=0;gg<FF;gg++) ds += dfS[w*FF*LL + gg*LL + 0]*Wscs[g*65+gg];  // lane = f
    ds1out[(size_t)n*FF+g] = ds;
  }
#pragma unroll
  for(int l=0;l<LL;l++){
    __syncthreads();
    for(int i=t;i<FF*FF;i+=256){ int a=i>>6,b=i&63; Wl[a*65+b]=Wlin[(size_t)l*FF*FF+i]; }
    __syncthreads();
    float da=0.f;
#pragma unroll
    for(int gg=0;gg<FF;gg++) da += dfS[w*FF*LL + gg*LL + l]*Wl[g*65+gg];  // lane = f
    dagg[((size_t)n*FF+g)*LL+l] = da;
  }
}

// ---------------- fused edge backward ----------------
// 8 edges/block (2 per wave). Recomputes MLP fwd, tw, then adjoints.
template<int LAYER>
__global__ __launch_bounds__(256,2) void k_edge_bwd(
    const float* __restrict__ csh, const float* __restrict__ cef,
    const float* __restrict__ cr, const float* __restrict__ cvec,
    const int* __restrict__ csnd, const int* __restrict__ crcv, const int* __restrict__ cnt,
    const float* __restrict__ src,
    const float* __restrict__ W1, const float* __restrict__ W2,
    const float* __restrict__ W3, const float* __restrict__ W4,
    const float* __restrict__ dagg,
    float* __restrict__ ds1,     // L2 only
    float* __restrict__ dvec,    // L2: write, L1: read
    float* __restrict__ dpos){   // L1 only
  if(blockIdx.x*8 >= cnt[1]) return;
  __shared__ float W1s[NBB*FF];
  __shared__ float W2s[FF*65], W3s[FF*65];
  __shared__ float h1S[8*FF], h2S[8*FF], h3S[8*FF];
  __shared__ float shs[8*LL], efs[8*NBB];
  __shared__ int sndS[8], rcvS[8];
  __shared__ float W4c[4*576];
  __shared__ float redS[4*8*FF];
  __shared__ float redS2[32*8];
  __shared__ float dh3S[8*FF];
  __shared__ float dzS[8*FF];
  const int t=threadIdx.x, w=t>>6, f=t&63;
  const size_t e0=(size_t)blockIdx.x*8;
  for(int i=t;i<NBB*FF;i+=256) W1s[i]=W1[i];
  for(int i=t;i<FF*FF;i+=256){ int j=i>>6,c=i&63; W2s[j*65+c]=W2[i]; W3s[j*65+c]=W3[i]; }
  for(int i=t;i<8*LL;i+=256) shs[i]=csh[e0*LL+i];
  for(int i=t;i<8*NBB;i+=256) efs[i]=cef[e0*NBB+i];
  if(t<8){ sndS[t]=csnd[e0+t]; rcvS[t]=crcv[e0+t]; }
  __syncthreads();
  // recompute forward L1..L3
#pragma unroll
  for(int i=0;i<2;i++){
    int e=w*2+i; float z=0.f;
#pragma unroll
    for(int b=0;b<NBB;b++) z += efs[e*NBB+b]*W1s[b*FF+f];
    h1S[e*FF+f]=siluf(z);
  }
  __syncthreads();
#pragma unroll
  for(int i=0;i<2;i++){
    int e=w*2+i; float z=0.f;
#pragma unroll
    for(int j=0;j<FF;j++) z += h1S[e*FF+j]*W2s[j*65+f];
    h2S[e*FF+f]=siluf(z);
  }
  __syncthreads();
#pragma unroll
  for(int i=0;i<2;i++){
    int e=w*2+i; float z=0.f;
#pragma unroll
    for(int j=0;j<FF;j++) z += h2S[e*FF+j]*W3s[j*65+f];
    h3S[e*FF+f]=siluf(z);
  }
  __syncthreads();
  // recompute tw
  float tw[2][9];
#pragma unroll
  for(int i=0;i<2;i++)
#pragma unroll
    for(int l=0;l<LL;l++) tw[i][l]=0.f;
  for(int jc=0;jc<16;jc++){
    for(int i=t;i<4*576;i+=256) W4c[i]=W4[jc*(4*576)+i];
    __syncthreads();
#pragma unroll
    for(int j4=0;j4<4;j4++){
      int j=jc*4+j4;
      float wv[9];
#pragma unroll
      for(int l=0;l<LL;l++) wv[l]=W4c[j4*576+f*LL+l];
#pragma unroll
      for(int i=0;i<2;i++){
        float h3=h3S[(w*2+i)*FF+j];
#pragma unroll
        for(int l=0;l<LL;l++) tw[i][l]+=h3*wv[l];
      }
    }
    __syncthreads();
  }
  // adjoints at the message level
  float dtw[2][9], dsh[2][9];
#pragma unroll
  for(int i=0;i<2;i++){
    int e=w*2+i;
    int sn=sndS[e], rc=rcvS[e];
    const float* dmp = dagg + ((size_t)rc*FF+f)*LL;
    float dm[9];
#pragma unroll
    for(int l=0;l<LL;l++) dm[l]=dmp[l]*INV_AVG;
    float sv = src[(size_t)sn*FF+f];
    if(LAYER==2){
      float A=0.f;
#pragma unroll
      for(int l=0;l<LL;l++) A += dm[l]*shs[e*LL+l]*tw[i][l];
      atomicAdd(&ds1[(size_t)sn*FF+f], A);   // d_s1[snd,f]
    }
#pragma unroll
    for(int l=0;l<LL;l++) dsh[i][l] = wred(dm[l]*sv*tw[i][l]);
#pragma unroll
    for(int l=0;l<LL;l++) dtw[i][l] = dm[l]*sv*shs[e*LL+l];
  }
  // d_h3[j] = sum_k dtw[k]*W4[j,k] via chunked partials + LDS tree reduction
  for(int jc=0;jc<16;jc++){
    for(int i2=t;i2<4*576;i2+=256) W4c[i2]=W4[jc*(4*576)+i2];
    __syncthreads();
#pragma unroll
    for(int j4=0;j4<4;j4++){
#pragma unroll
      for(int i=0;i<2;i++){
        float p=0.f;
#pragma unroll
        for(int l=0;l<LL;l++) p += dtw[i][l]*W4c[j4*576+f*LL+l];
        redS[(j4*8 + (w*2+i))*FF + f] = p;
      }
    }
    __syncthreads();
    {
      int row=t>>3, seg=t&7;
      float s=0.f;
#pragma unroll
      for(int k=0;k<8;k++) s += redS[row*FF + seg*8 + k];
      redS2[t]=s;
    }
    __syncthreads();
    if(t<32){
      float s=0.f;
#pragma unroll
      for(int k=0;k<8;k++) s += redS2[t*8+k];
      int j4=t>>3, e=t&7;
      dh3S[e*FF + jc*4 + j4] = s;
    }
    __syncthreads();
  }
  // backprop the MLP chain, then geometry
#pragma unroll
  for(int i=0;i<2;i++){
    int e=w*2+i;
    float z3=0.f;
#pragma unroll
    for(int j=0;j<FF;j++) z3 += h2S[e*FF+j]*W3s[j*65+f];
    float sg3 = 1.f/(1.f+__expf(-z3));
    float dz3 = dh3S[e*FF+f]*sg3*(1.f + z3*(1.f-sg3));
    __syncthreads();
    dzS[e*FF+f]=dz3;
    __syncthreads();
    float dh2=0.f;
#pragma unroll
    for(int ff2=0;ff2<FF;ff2++) dh2 += dzS[e*FF+ff2]*W3s[f*65+ff2];
    float z2=0.f;
#pragma unroll
    for(int j=0;j<FF;j++) z2 += h1S[e*FF+j]*W2s[j*65+f];
    float sg2=1.f/(1.f+__expf(-z2));
    float dz2 = dh2*sg2*(1.f+z2*(1.f-sg2));
    __syncthreads();
    dzS[e*FF+f]=dz2;
    __syncthreads();
    float dh1=0.f;
#pragma unroll
    for(int ff2=0;ff2<FF;ff2++) dh1 += dzS[e*FF+ff2]*W2s[f*65+ff2];
    float z1=0.f;
#pragma unroll
    for(int b=0;b<NBB;b++) z1 += efs[e*NBB+b]*W1s[b*FF+f];
    float sg1=1.f/(1.f+__expf(-z1));
    float dz1 = dh1*sg1*(1.f+z1*(1.f-sg1));
    float def[8];
#pragma unroll
    for(int b=0;b<NBB;b++) def[b]=wred(dz1*W1s[b*FF+f]);
    // geometry gradient (all lanes compute; lane 0 writes)
    size_t eg = e0+e;
    float r = cr[eg];
    float invr = 1.f/r;
    float vx=cvec[eg*3+0], vy=cvec[eg*3+1], vz=cvec[eg*3+2];
    float ux=vx*invr, uy=vy*invr, uz=vz*invr;
    float xr=r*(1.f/RMAXF);
    float x2=xr*xr, x4=x2*x2, x5=x4*xr, x6=x5*xr, x7=x6*xr;
    float env = 1.f-28.f*x6+48.f*x7-21.f*x7*xr;
    float envd = (-168.f*x5+336.f*x6-168.f*x7)*(1.f/RMAXF);
    const float CB=0.632455532f;
    float dr=0.f;
#pragma unroll
    for(int b=0;b<NBB;b++){
      float a=(b+1)*(PI_F/RMAXF);
      float ar=a*r;
      float sn_=sinf(ar), cs_=cosf(ar);
      float bess = CB*sn_*invr;
      // Taylor guard: avoids f32 cancellation at tiny r (self-edges)
      float bessd = (ar<1e-2f) ? (-CB*a*a*a*r*(1.f/3.f))
                               : (CB*(a*cs_-sn_*invr)*invr);
      dr += def[b]*(bessd*env + bess*envd);
    }
    const float s3=1.7320508f, s5=2.23606798f, s15=3.87298335f;
    float d1=dsh[i][1],d2=dsh[i][2],d3=dsh[i][3],d4=dsh[i][4],
          d5=dsh[i][5],d6=dsh[i][6],d7=dsh[i][7],d8=dsh[i][8];
    float dux = s3*d1 + s15*(uy*d4 + uz*d7 + ux*d8);
    float duy = s3*d2 + s15*(ux*d4 + uz*d5 - uy*d8);
    float duz = s3*d3 + s15*(uy*d5 + ux*d7) + 3.f*s5*uz*d6;
    float udd = ux*dux+uy*duy+uz*duz;
    float dvx = dr*ux + (dux-ux*udd)*invr;
    float dvy = dr*uy + (duy-uy*udd)*invr;
    float dvz = dr*uz + (duz-uz*udd)*invr;
    if(f==0){
      if(LAYER==2){
        dvec[eg*3+0]=dvx; dvec[eg*3+1]=dvy; dvec[eg*3+2]=dvz;
      } else {
        int sn=sndS[e], rc=rcvS[e];
        float tx=dvec[eg*3+0]+dvx, ty=dvec[eg*3+1]+dvy, tz=dvec[eg*3+2]+dvz;
        atomicAdd(&dpos[rc*3+0], tx); atomicAdd(&dpos[rc*3+1], ty); atomicAdd(&dpos[rc*3+2], tz);
        atomicAdd(&dpos[sn*3+0],-tx); atomicAdd(&dpos[sn*3+1],-ty); atomicAdd(&dpos[sn*3+2],-tz);
      }
    }
  }
}

__global__ __launch_bounds__(256) void k_forces(const float* __restrict__ dpos,
                                                float* __restrict__ forces){
  int i = blockIdx.x*256+threadIdx.x;
  if(i < NNODES*3) forces[i] = -dpos[i];
}

extern "C" void kernel_launch(void* const* d_in, const int* in_sizes, int n_in,
                              void* d_out, int out_size, void* d_ws, size_t ws_size,
                              hipStream_t stream){
  (void)in_sizes; (void)n_in; (void)out_size; (void)ws_size;
  const float* pos    = (const float*)d_in[0];
  const float* attrs  = (const float*)d_in[1];
  const float* shifts = (const float*)d_in[2];
  const float* ae     = (const float*)d_in[3];
  const float* Wemb   = (const float*)d_in[4];
  const float* R1W1   = (const float*)d_in[5];
  const float* R1W2   = (const float*)d_in[6];
  const float* R1W3   = (const float*)d_in[7];
  const float* R1W4   = (const float*)d_in[8];
  const float* R2W1   = (const float*)d_in[9];
  const float* R2W2   = (const float*)d_in[10];
  const float* R2W3   = (const float*)d_in[11];
  const float* R2W4   = (const float*)d_in[12];
  const float* Wlin1  = (const float*)d_in[13];
  const float* Wsc1   = (const float*)d_in[14];
  const float* Wpr1   = (const float*)d_in[15];
  const float* wrd1   = (const float*)d_in[16];
  const float* Wlin2  = (const float*)d_in[17];
  const float* Wsc2   = (const float*)d_in[18];
  const float* Wpr2   = (const float*)d_in[19];
  const float* Wr1    = (const float*)d_in[20];
  const float* wr2    = (const float*)d_in[21];
  const int*   eidx   = (const int*)d_in[22];
  const int*   batch  = (const int*)d_in[23];

  float* out = (float*)d_out;
  float* ws  = (float*)d_ws;
  float* totE   = out;          // 32
  float* nodeE  = out + 32;     // 10000
  float* forces = out + 10032;  // 30000
  float* nfeats = out + 40032;  // 10000*1152

  float* h0   = ws + O_H0;
  float* s1   = ws + O_S1;
  float* agg1 = ws + O_AGG1;
  float* agg2 = ws + O_AGG2;
  float* f1   = ws + O_F1;
  float* f2   = ws + O_F2;
  float* c1   = ws + O_C1;
  float* c2   = ws + O_C2;
  float* ds1  = ws + O_DS1;
  float* csh  = ws + O_CSH;
  float* cef  = ws + O_CEF;
  float* crr  = ws + O_CR;
  float* cvec = ws + O_CVEC;
  float* dvec = ws + O_DVEC;
  float* dpos = ws + O_DPOS;
  int* csnd = (int*)(ws + O_CSND);
  int* crcv = (int*)(ws + O_CRCV);
  int* cnt  = (int*)(ws + O_CNT);
  float* dagg2 = agg1;   // alias: agg1 dead after node-fwd L1
  float* dagg1 = agg2;   // alias: agg2 dead after node-fwd L2

  hipMemsetAsync(totE, 0, 32*sizeof(float), stream);
  hipMemsetAsync(agg1, 0, (size_t)2*5760000*sizeof(float), stream); // agg1+agg2 contiguous
  hipMemsetAsync(dpos, 0, 30000*sizeof(float), stream);
  hipMemsetAsync(cnt,  0, 2*sizeof(int), stream);

  k_embed<<<2500,256,0,stream>>>(attrs, Wemb, ae, batch, h0, totE, nodeE);
  k_geom<<<1000,256,0,stream>>>(pos, shifts, eidx, csh, cef, crr, cvec, csnd, crcv, cnt);
  k_pad<<<1,32,0,stream>>>(csh, cef, crr, cvec, csnd, crcv, cnt);

  k_edge_fwd<<<8000,256,0,stream>>>(csh,cef,csnd,crcv,cnt, h0,
                                    R1W1,R1W2,R1W3,R1W4, agg1);
  k_node_fwd<1><<<2500,256,0,stream>>>(agg1, h0, batch, Wlin1, Wsc1, Wpr1,
                                       wrd1, nullptr, nullptr,
                                       f1, c1, s1, nfeats, nodeE, totE);
  k_edge_fwd<<<8000,256,0,stream>>>(csh,cef,csnd,crcv,cnt, s1,
                                    R2W1,R2W2,R2W3,R2W4, agg2);
  k_node_fwd<2><<<2500,256,0,stream>>>(agg2, s1, batch, Wlin2, Wsc2, Wpr2,
                                       nullptr, Wr1, wr2,
                                       f2, c2, nullptr, nfeats, nodeE, totE);

  k_node_bwd<2><<<2500,256,0,stream>>>(f2, c2, Wlin2, Wpr2, Wsc2, Wr1, wr2,
                                       nullptr, nullptr, nfeats, dagg2, ds1);
  k_edge_bwd<2><<<32000,256,0,stream>>>(csh,cef,crr,cvec,csnd,crcv,cnt, s1,
                                        R2W1,R2W2,R2W3,R2W4, dagg2,
                                        ds1, dvec, nullptr);
  k_node_bwd<1><<<2500,256,0,stream>>>(f1, c1, Wlin1, Wpr1, nullptr, nullptr, nullptr,
                                       wrd1, ds1, nullptr, dagg1, nullptr);
  k_edge_bwd<1><<<32000,256,0,stream>>>(csh,cef,crr,cvec,csnd,crcv,cnt, h0,
                                        R1W1,R1W2,R1W3,R1W4, dagg1,
                                        nullptr, dvec, dpos);
  k_forces<<<118,256,0,stream>>>(dpos, forces);
}

// Round 2
// 5640.617 us; speedup vs baseline: 1.4896x; 1.4896x over previous
//
#include <hip/hip_runtime.h>
#include <cstddef>

#define NNODES 10000
#define NEDGES 256000
#define NGRAPH 32
#define NELEM  10
#define FF     64
#define LL     9
#define NBB    8
#define HIDN   16
#define RMAXF  5.0f
#define INV_AVG 0.0390625f   /* 1/25.6 exact */
#define PI_F   3.14159265358979f
#define ECAP   98304         /* compact-edge capacity; expected active ~74.7k (30+ sigma margin) */

// ---------------- workspace layout (float elements), ~115.4 MB ----------------
constexpr size_t O_H0    = 0;           // 640000
constexpr size_t O_S1    = 640000;      // 640000
constexpr size_t O_AGG1  = 1280000;     // 5760000 (fwd agg1; reused as d_agg2 in bwd)
constexpr size_t O_AGG2  = 7040000;     // 5760000 (fwd agg2; reused as d_agg1 in bwd)
constexpr size_t O_F1    = 12800000;    // 5760000
constexpr size_t O_F2    = 18560000;    // 5760000
constexpr size_t O_C1    = 24320000;    // 640000
constexpr size_t O_C2    = 24960000;    // 640000
constexpr size_t O_DS1   = 25600000;    // 640000
constexpr size_t O_CSH   = 26240000;    // ECAP*9  = 884736
constexpr size_t O_CEF   = 27124736;    // ECAP*8  = 786432
constexpr size_t O_CR    = 27911168;    // ECAP
constexpr size_t O_CVEC  = 28009472;    // ECAP*3  = 294912
constexpr size_t O_DVEC  = 28304384;    // ECAP*3  = 294912
constexpr size_t O_DPOS  = 28599296;    // 30000
constexpr size_t O_CSND  = 28629296;    // ECAP ints
constexpr size_t O_CRCV  = 28727600;    // ECAP ints
constexpr size_t O_HIST  = 28825904;    // 10000 ints
constexpr size_t O_CURS  = 28835904;    // 10001 ints
constexpr size_t O_CNT   = 28845905;    // 2 ints: [0]=count, [1]=count rounded to 32

__device__ __forceinline__ float siluf(float z){
  return z*(1.f/(1.f+__expf(-z)));
}
__device__ __forceinline__ float wred(float v){
#pragma unroll
  for(int o=32;o>0;o>>=1) v += __shfl_xor(v,o,64);
  return v;
}

// ---------------- node embedding + e0 ----------------
__global__ __launch_bounds__(256) void k_embed(
    const float* __restrict__ attrs, const float* __restrict__ Wemb,
    const float* __restrict__ ae, const int* __restrict__ batch,
    float* __restrict__ h0, float* __restrict__ totE, float* __restrict__ nodeE){
  int t = blockIdx.x*256 + threadIdx.x;
  int n = t >> 6, f = t & 63;
  float acc = 0.f;
#pragma unroll
  for(int k=0;k<NELEM;k++) acc += attrs[n*NELEM+k]*Wemb[k*FF+f];
  h0[(size_t)n*FF+f] = acc;
  if(f==0){
    float e0 = 0.f;
#pragma unroll
    for(int k=0;k<NELEM;k++) e0 += attrs[n*NELEM+k]*ae[k];
    nodeE[n] = e0;
    atomicAdd(&totE[batch[n]], e0);
  }
}

// ---------------- pass 1: histogram of receivers over active edges ----------------
__global__ __launch_bounds__(256) void k_count(
    const float* __restrict__ pos, const float* __restrict__ shifts,
    const int* __restrict__ eidx, int* __restrict__ hist){
  int e = blockIdx.x*256 + threadIdx.x;
  int sn = eidx[e], rc = eidx[NEDGES + e];
  float vx = pos[rc*3+0]-pos[sn*3+0]+shifts[(size_t)e*3+0];
  float vy = pos[rc*3+1]-pos[sn*3+1]+shifts[(size_t)e*3+1];
  float vz = pos[rc*3+2]-pos[sn*3+2]+shifts[(size_t)e*3+2];
  float r2 = vx*vx+vy*vy+vz*vz+1e-12f;
  if(r2 < RMAXF*RMAXF) atomicAdd(&hist[rc], 1);
}

// ---------------- pass 2: exclusive scan (single block, 1024 threads) ----------------
__global__ __launch_bounds__(1024) void k_scan(
    const int* __restrict__ hist, int* __restrict__ cursor, int* __restrict__ cnt){
  __shared__ int buf[1024];
  __shared__ int carryS;
  int t = threadIdx.x;
  if(t==0) carryS = 0;
  __syncthreads();
  for(int c=0;c<10;c++){
    int i = c*1024 + t;
    int v = (i<NNODES)? hist[i] : 0;
    buf[t]=v;
    __syncthreads();
    for(int off=1; off<1024; off<<=1){
      int x = (t>=off)? buf[t-off] : 0;
      __syncthreads();
      buf[t] += x;
      __syncthreads();
    }
    int incl = buf[t];
    int base = carryS;
    if(i<NNODES) cursor[i] = base + incl - v;   // exclusive prefix
    __syncthreads();
    if(t==1023) carryS += buf[1023];
    __syncthreads();
  }
  if(t==0){
    int n = carryS;
    cnt[0] = n;
    cnt[1] = (n+31)&~31;
  }
}

// ---------------- pass 3: compute geometry, scatter into rcv-sorted order ----------------
__global__ __launch_bounds__(256) void k_scatter(
    const float* __restrict__ pos, const float* __restrict__ shifts, const int* __restrict__ eidx,
    int* __restrict__ cursor,
    float* __restrict__ csh, float* __restrict__ cef, float* __restrict__ cr,
    float* __restrict__ cvec, int* __restrict__ csnd, int* __restrict__ crcv){
  int e = blockIdx.x*256 + threadIdx.x;
  int sn = eidx[e], rc = eidx[NEDGES + e];
  float vx = pos[rc*3+0]-pos[sn*3+0]+shifts[(size_t)e*3+0];
  float vy = pos[rc*3+1]-pos[sn*3+1]+shifts[(size_t)e*3+1];
  float vz = pos[rc*3+2]-pos[sn*3+2]+shifts[(size_t)e*3+2];
  float r2 = vx*vx+vy*vy+vz*vz+1e-12f;
  if(r2 >= RMAXF*RMAXF) return;
  float r = sqrtf(r2);
  int i = atomicAdd(&cursor[rc], 1);
  csnd[i]=sn; crcv[i]=rc; cr[i]=r;
  cvec[(size_t)i*3+0]=vx; cvec[(size_t)i*3+1]=vy; cvec[(size_t)i*3+2]=vz;
  float inv = 1.f/r, x=vx*inv, y=vy*inv, z=vz*inv;
  const float s3=1.7320508f, s5=2.23606798f, s15=3.87298335f;
  float* sh = csh + (size_t)i*LL;
  sh[0]=1.f; sh[1]=s3*x; sh[2]=s3*y; sh[3]=s3*z; sh[4]=s15*x*y; sh[5]=s15*y*z;
  sh[6]=0.5f*s5*(3.f*z*z-1.f); sh[7]=s15*x*z; sh[8]=0.5f*s15*(x*x-y*y);
  float xr = r*(1.f/RMAXF);
  float x2=xr*xr, x4=x2*x2, x6=x4*x2, x7=x6*xr, x8=x7*xr;
  float env = 1.f - 28.f*x6 + 48.f*x7 - 21.f*x8;
  const float CB = 0.632455532f;
#pragma unroll
  for(int b=0;b<NBB;b++){
    float a = (b+1)*(PI_F/RMAXF);
    cef[(size_t)i*NBB+b] = CB*sinf(a*r)*inv*env;
  }
}

// pad compact list to multiple of 32 with benign zero edges (rcv = last node: adds 0)
__global__ void k_pad(float* csh, float* cef, float* cr, float* cvec,
                      int* csnd, int* crcv, const int* cnt){
  int n = cnt[0];
  int nr = cnt[1];
  int i = n + threadIdx.x;
  if(i < nr){
    csnd[i]=0; crcv[i]=NNODES-1; cr[i]=1.f;
    cvec[(size_t)i*3+0]=0.f; cvec[(size_t)i*3+1]=0.f; cvec[(size_t)i*3+2]=1.f;
    for(int l=0;l<LL;l++) csh[(size_t)i*LL+l]=0.f;
    for(int b=0;b<NBB;b++) cef[(size_t)i*NBB+b]=0.f;
  }
}

// ---------------- fused edge forward: MLP -> tw -> segmented run-reduction ----------------
// 32 rcv-sorted edges/block, 8 per wave. Interior runs: plain stores. Boundary runs: atomic.
__global__ __launch_bounds__(256,2) void k_edge_fwd(
    const float* __restrict__ csh, const float* __restrict__ cef,
    const int* __restrict__ csnd, const int* __restrict__ crcv, const int* __restrict__ cnt,
    const float* __restrict__ src,
    const float* __restrict__ W1, const float* __restrict__ W2,
    const float* __restrict__ W3, const float* __restrict__ W4,
    float* __restrict__ agg){
  const int cnt32 = cnt[1];
  if((int)(blockIdx.x*32) >= cnt32) return;
  __shared__ float W1s[NBB*FF];
  __shared__ float W2s[FF*65], W3s[FF*65];
  __shared__ float hA[32*FF], hB[32*FF];   // hA reused as msgL in epilogue
  __shared__ float shs[32*LL], efs[32*NBB];
  __shared__ int   sndS[32], rcvS[32];
  __shared__ float W4c[4*576];
  const int t = threadIdx.x;
  const size_t e0 = (size_t)blockIdx.x*32;
  for(int i=t;i<NBB*FF;i+=256) W1s[i]=W1[i];
  for(int i=t;i<FF*FF;i+=256){ int j=i>>6, c=i&63; W2s[j*65+c]=W2[i]; W3s[j*65+c]=W3[i]; }
  for(int i=t;i<32*LL;i+=256) shs[i]=csh[e0*LL+i];
  for(int i=t;i<32*NBB;i+=256) efs[i]=cef[e0*NBB+i];
  if(t<32){ sndS[t]=csnd[e0+t]; rcvS[t]=crcv[e0+t]; }
  __syncthreads();
  const int w=t>>6, f=t&63;
#pragma unroll
  for(int i=0;i<8;i++){
    int e=w*8+i; float z=0.f;
#pragma unroll
    for(int b=0;b<NBB;b++) z += efs[e*NBB+b]*W1s[b*FF+f];
    hA[e*FF+f]=siluf(z);
  }
  __syncthreads();
#pragma unroll
  for(int i=0;i<8;i++){
    int e=w*8+i; float z=0.f;
#pragma unroll
    for(int j=0;j<FF;j++) z += hA[e*FF+j]*W2s[j*65+f];
    hB[e*FF+f]=siluf(z);
  }
  __syncthreads();
#pragma unroll
  for(int i=0;i<8;i++){
    int e=w*8+i; float z=0.f;
#pragma unroll
    for(int j=0;j<FF;j++) z += hB[e*FF+j]*W3s[j*65+f];
    hA[e*FF+f]=siluf(z);
  }
  __syncthreads();
  float tw[8][9];
#pragma unroll
  for(int i=0;i<8;i++)
#pragma unroll
    for(int l=0;l<LL;l++) tw[i][l]=0.f;
  for(int jc=0;jc<16;jc++){
    for(int i=t;i<4*576;i+=256) W4c[i]=W4[jc*(4*576)+i];
    __syncthreads();
#pragma unroll
    for(int j4=0;j4<4;j4++){
      int j=jc*4+j4;
      float wv[9];
#pragma unroll
      for(int l=0;l<LL;l++) wv[l]=W4c[j4*576 + f*LL + l];
#pragma unroll
      for(int i=0;i<8;i++){
        float h3 = hA[(w*8+i)*FF + j];
#pragma unroll
        for(int l=0;l<LL;l++) tw[i][l] += h3*wv[l];
      }
    }
    __syncthreads();
  }
  // --- epilogue: per-l LDS run reduction ---
  float sv[8];
#pragma unroll
  for(int i=0;i<8;i++) sv[i] = src[(size_t)sndS[w*8+i]*FF + f];
  const bool leftStraddle  = (e0>0) && (crcv[e0-1] == rcvS[0]);
  const bool rightStraddle = ((int)(e0+32) < cnt32) && (crcv[e0+32] == rcvS[31]);
  float* msgL = hA;  // h3 dead now
#pragma unroll
  for(int l=0;l<LL;l++){
#pragma unroll
    for(int i=0;i<8;i++){
      int e=w*8+i;
      msgL[e*FF+f] = sv[i]*shs[e*LL+l]*tw[i][l]*INV_AVG;
    }
    __syncthreads();
    // wave w handles run-heads located in slots [w*8, w*8+8)
#pragma unroll
    for(int s0=0;s0<8;s0++){
      int s = w*8+s0;
      int rc = rcvS[s];
      bool head = (s==0) || (rcvS[s-1]!=rc);
      if(head){
        int L=1;
        while(s+L<32 && rcvS[s+L]==rc) L++;
        float sum=0.f;
        for(int k=0;k<L;k++) sum += msgL[(s+k)*FF+f];
        bool atom = (s==0 && leftStraddle) || (s+L==32 && rightStraddle);
        float* ap = &agg[((size_t)rc*FF+f)*LL + l];
        if(atom) atomicAdd(ap, sum); else *ap = sum;
      }
    }
    __syncthreads();
  }
}

// ---------------- node forward ----------------
template<int LAYER>
__global__ __launch_bounds__(256,2) void k_node_fwd(
    const float* __restrict__ agg, const float* __restrict__ src,
    const int* __restrict__ batch,
    const float* __restrict__ Wlin, const float* __restrict__ Wsc,
    const float* __restrict__ Wpr,
    const float* __restrict__ wread,
    const float* __restrict__ Wr1, const float* __restrict__ wr2,
    float* __restrict__ feats, float* __restrict__ cbuf,
    float* __restrict__ s1out,
    float* __restrict__ nfeats, float* __restrict__ nodeE, float* __restrict__ totE){
  __shared__ float Wl[FF*65], Wscs[FF*65], Wprs[FF*65];
  __shared__ float Wr1s[FF*HIDN];
  __shared__ float av[4*FF], invS[4*FF];
  const int t=threadIdx.x, w=t>>6, g=t&63;
  const int n = blockIdx.x*4 + w;
  for(int i=t;i<FF*FF;i+=256){ int a=i>>6,b=i&63; Wscs[a*65+b]=Wsc[i]; Wprs[a*65+b]=Wpr[i]; }
  if(LAYER==2) for(int i=t;i<FF*HIDN;i+=256) Wr1s[i]=Wr1[i];
  float fr[9];
#pragma unroll
  for(int l=0;l<LL;l++){
    __syncthreads();
    for(int i=t;i<FF*FF;i+=256){ int a=i>>6,b=i&63; Wl[a*65+b]=Wlin[(size_t)l*FF*FF+i]; }
    av[t] = agg[((size_t)n*FF + g)*LL + l];
    __syncthreads();
    float acc=0.f;
#pragma unroll
    for(int ff=0;ff<FF;ff++) acc += av[w*FF+ff]*Wl[ff*65+g];
    fr[l]=acc;
  }
  __syncthreads();
  av[t] = src[(size_t)n*FF + g];
  __syncthreads();
  float sacc=0.f;
#pragma unroll
  for(int ff=0;ff<FF;ff++) sacc += av[w*FF+ff]*Wscs[ff*65+g];
  fr[0]+=sacc;
  float* fp = feats + ((size_t)n*FF+g)*LL;
  float iv=0.f;
#pragma unroll
  for(int l=0;l<LL;l++){ fp[l]=fr[l]; iv+=fr[l]*fr[l]; }
  invS[t]=iv;
  __syncthreads();
  float c=1.f;
#pragma unroll
  for(int gg=0;gg<FF;gg++) c += invS[w*FF+gg]*Wprs[gg*65+g];
  cbuf[(size_t)n*FF+g]=c;
  float s0 = fr[0]*c;
  float* nf = nfeats + (size_t)n*(2*FF*LL) + (LAYER==2 ? FF*LL : 0) + g*LL;
#pragma unroll
  for(int l=0;l<LL;l++) nf[l]=fr[l]*c;
  if(LAYER==1) s1out[(size_t)n*FF+g]=s0;
  float epart;
  if(LAYER==1){
    epart = s0*wread[g];
  } else {
    __syncthreads();
    invS[t]=s0;
    __syncthreads();
    epart=0.f;
    if(g<HIDN){
      float tt=0.f;
#pragma unroll
      for(int gg=0;gg<FF;gg++) tt += invS[w*FF+gg]*Wr1s[gg*HIDN+g];
      epart = siluf(tt)*wr2[g];
    }
  }
  float esum = wred(epart);
  if(g==0){
    nodeE[n] += esum;
    atomicAdd(&totE[batch[n]], esum);
  }
}

// ---------------- node backward ----------------
template<int LAYER>
__global__ __launch_bounds__(256,2) void k_node_bwd(
    const float* __restrict__ feats, const float* __restrict__ cbuf,
    const float* __restrict__ Wlin, const float* __restrict__ Wpr,
    const float* __restrict__ Wsc,
    const float* __restrict__ Wr1, const float* __restrict__ wr2,
    const float* __restrict__ wread, const float* __restrict__ ds1in,
    const float* __restrict__ nfeats,
    float* __restrict__ dagg, float* __restrict__ ds1out){
  __shared__ float Wl[FF*65], Wprs[FF*65], Wscs[FF*65];
  __shared__ float Wr1s[FF*HIDN];
  __shared__ float dfS[4*FF*LL];
  __shared__ float rowS[4*FF];
  __shared__ float dtS[4*HIDN];
  const int t=threadIdx.x, w=t>>6, g=t&63;
  const int n = blockIdx.x*4 + w;
  for(int i=t;i<FF*FF;i+=256){ int a=i>>6,b=i&63; Wprs[a*65+b]=Wpr[i]; }
  if(LAYER==2){
    for(int i=t;i<FF*FF;i+=256){ int a=i>>6,b=i&63; Wscs[a*65+b]=Wsc[i]; }
    for(int i=t;i<FF*HIDN;i+=256) Wr1s[i]=Wr1[i];
  }
  __syncthreads();
  float dh0;
  if(LAYER==2){
    rowS[t] = nfeats[(size_t)n*(2*FF*LL) + FF*LL + g*LL + 0];
    __syncthreads();
    if(g<HIDN){
      float tt=0.f;
#pragma unroll
      for(int gg=0;gg<FF;gg++) tt += rowS[w*FF+gg]*Wr1s[gg*HIDN+g];
      float sg = 1.f/(1.f+__expf(-tt));
      dtS[w*HIDN+g] = sg*(1.f + tt*(1.f-sg)) * wr2[g];
    }
    __syncthreads();
    dh0=0.f;
#pragma unroll
    for(int h=0;h<HIDN;h++) dh0 += dtS[w*HIDN+h]*Wr1s[g*HIDN+h];
  } else {
    dh0 = wread[g] + ds1in[(size_t)n*FF+g];
  }
  const float* fp = feats + ((size_t)n*FF+g)*LL;
  float f0 = fp[0];
  __syncthreads();
  rowS[t] = dh0*f0;
  __syncthreads();
  float dinv=0.f;
#pragma unroll
  for(int gg=0;gg<FF;gg++) dinv += rowS[w*FF+gg]*Wprs[g*65+gg];
  float c = cbuf[(size_t)n*FF+g];
  float df[9];
#pragma unroll
  for(int l=0;l<LL;l++) df[l] = 2.f*dinv*fp[l];
  df[0] += dh0*c;
#pragma unroll
  for(int l=0;l<LL;l++) dfS[w*FF*LL + g*LL + l] = df[l];
  __syncthreads();
  if(LAYER==2){
    float ds=0.f;
#pragma unroll
    for(int gg=0;gg<FF;gg++) ds += dfS[w*FF*LL + gg*LL + 0]*Wscs[g*65+gg];
    ds1out[(size_t)n*FF+g] = ds;
  }
#pragma unroll
  for(int l=0;l<LL;l++){
    __syncthreads();
    for(int i=t;i<FF*FF;i+=256){ int a=i>>6,b=i&63; Wl[a*65+b]=Wlin[(size_t)l*FF*FF+i]; }
    __syncthreads();
    float da=0.f;
#pragma unroll
    for(int gg=0;gg<FF;gg++) da += dfS[w*FF*LL + gg*LL + l]*Wl[g*65+gg];
    dagg[((size_t)n*FF+g)*LL+l] = da;
  }
}

// ---------------- fused edge backward (single W4 pass) ----------------
template<int LAYER>
__global__ __launch_bounds__(256,2) void k_edge_bwd(
    const float* __restrict__ csh, const float* __restrict__ cef,
    const float* __restrict__ cr, const float* __restrict__ cvec,
    const int* __restrict__ csnd, const int* __restrict__ crcv, const int* __restrict__ cnt,
    const float* __restrict__ src,
    const float* __restrict__ W1, const float* __restrict__ W2,
    const float* __restrict__ W3, const float* __restrict__ W4,
    const float* __restrict__ dagg,
    float* __restrict__ ds1,
    float* __restrict__ dvec,
    float* __restrict__ dpos){
  if((int)(blockIdx.x*8) >= cnt[1]) return;
  __shared__ float W1s[NBB*FF];
  __shared__ float W2s[FF*65], W3s[FF*65];
  __shared__ float h1S[8*FF], h2S[8*FF], h3S[8*FF];
  __shared__ float shs[8*LL], efs[8*NBB];
  __shared__ int sndS[8], rcvS[8];
  __shared__ float W4c[4*576];
  __shared__ float redS[4*8*FF];
  __shared__ float redS2[32*8];
  __shared__ float dh3S[8*FF];
  __shared__ float dzS[8*FF];
  const int t=threadIdx.x, w=t>>6, f=t&63;
  const size_t e0=(size_t)blockIdx.x*8;
  for(int i=t;i<NBB*FF;i+=256) W1s[i]=W1[i];
  for(int i=t;i<FF*FF;i+=256){ int j=i>>6,c=i&63; W2s[j*65+c]=W2[i]; W3s[j*65+c]=W3[i]; }
  for(int i=t;i<8*LL;i+=256) shs[i]=csh[e0*LL+i];
  for(int i=t;i<8*NBB;i+=256) efs[i]=cef[e0*NBB+i];
  if(t<8){ sndS[t]=csnd[e0+t]; rcvS[t]=crcv[e0+t]; }
  __syncthreads();
  // forward recompute
#pragma unroll
  for(int i=0;i<2;i++){
    int e=w*2+i; float z=0.f;
#pragma unroll
    for(int b=0;b<NBB;b++) z += efs[e*NBB+b]*W1s[b*FF+f];
    h1S[e*FF+f]=siluf(z);
  }
  __syncthreads();
#pragma unroll
  for(int i=0;i<2;i++){
    int e=w*2+i; float z=0.f;
#pragma unroll
    for(int j=0;j<FF;j++) z += h1S[e*FF+j]*W2s[j*65+f];
    h2S[e*FF+f]=siluf(z);
  }
  __syncthreads();
#pragma unroll
  for(int i=0;i<2;i++){
    int e=w*2+i; float z=0.f;
#pragma unroll
    for(int j=0;j<FF;j++) z += h2S[e*FF+j]*W3s[j*65+f];
    h3S[e*FF+f]=siluf(z);
  }
  __syncthreads();
  // message-level adjoints that don't need tw
  float dtw[2][9], sv[2];
#pragma unroll
  for(int i=0;i<2;i++){
    int e=w*2+i;
    int sn=sndS[e], rc=rcvS[e];
    sv[i] = src[(size_t)sn*FF+f];
    const float* dmp = dagg + ((size_t)rc*FF+f)*LL;
#pragma unroll
    for(int l=0;l<LL;l++) dtw[i][l] = dmp[l]*INV_AVG*sv[i]*shs[e*LL+l];
  }
  // single W4 pass: tw accumulate + dh3 partials
  float tw[2][9];
#pragma unroll
  for(int i=0;i<2;i++)
#pragma unroll
    for(int l=0;l<LL;l++) tw[i][l]=0.f;
  for(int jc=0;jc<16;jc++){
    for(int i2=t;i2<4*576;i2+=256) W4c[i2]=W4[jc*(4*576)+i2];
    __syncthreads();
#pragma unroll
    for(int j4=0;j4<4;j4++){
      int j=jc*4+j4;
      float wv[9];
#pragma unroll
      for(int l=0;l<LL;l++) wv[l]=W4c[j4*576+f*LL+l];
#pragma unroll
      for(int i=0;i<2;i++){
        float h3=h3S[(w*2+i)*FF+j];
        float p=0.f;
#pragma unroll
        for(int l=0;l<LL;l++){ tw[i][l]+=h3*wv[l]; p += dtw[i][l]*wv[l]; }
        redS[(j4*8 + (w*2+i))*FF + f] = p;
      }
    }
    __syncthreads();
    {
      int row=t>>3, seg=t&7;
      float s=0.f;
#pragma unroll
      for(int k=0;k<8;k++) s += redS[row*FF + seg*8 + k];
      redS2[t]=s;
    }
    __syncthreads();
    if(t<32){
      float s=0.f;
#pragma unroll
      for(int k=0;k<8;k++) s += redS2[t*8+k];
      int j4=t>>3, e=t&7;
      dh3S[e*FF + jc*4 + j4] = s;
    }
    __syncthreads();
  }
  // dsh, ds1(A) — need tw
  float dsh[2][9];
#pragma unroll
  for(int i=0;i<2;i++){
    int e=w*2+i;
    int sn=sndS[e], rc=rcvS[e];
    const float* dmp = dagg + ((size_t)rc*FF+f)*LL;
    float dm[9];
#pragma unroll
    for(int l=0;l<LL;l++) dm[l]=dmp[l]*INV_AVG;
    if(LAYER==2){
      float A=0.f;
#pragma unroll
      for(int l=0;l<LL;l++) A += dm[l]*shs[e*LL+l]*tw[i][l];
      atomicAdd(&ds1[(size_t)sn*FF+f], A);
    }
#pragma unroll
    for(int l=0;l<LL;l++) dsh[i][l] = wred(dm[l]*sv[i]*tw[i][l]);
  }
  // MLP chain backprop + geometry
#pragma unroll
  for(int i=0;i<2;i++){
    int e=w*2+i;
    float z3=0.f;
#pragma unroll
    for(int j=0;j<FF;j++) z3 += h2S[e*FF+j]*W3s[j*65+f];
    float sg3 = 1.f/(1.f+__expf(-z3));
    float dz3 = dh3S[e*FF+f]*sg3*(1.f + z3*(1.f-sg3));
    __syncthreads();
    dzS[e*FF+f]=dz3;
    __syncthreads();
    float dh2=0.f;
#pragma unroll
    for(int ff2=0;ff2<FF;ff2++) dh2 += dzS[e*FF+ff2]*W3s[f*65+ff2];
    float z2=0.f;
#pragma unroll
    for(int j=0;j<FF;j++) z2 += h1S[e*FF+j]*W2s[j*65+f];
    float sg2=1.f/(1.f+__expf(-z2));
    float dz2 = dh2*sg2*(1.f+z2*(1.f-sg2));
    __syncthreads();
    dzS[e*FF+f]=dz2;
    __syncthreads();
    float dh1=0.f;
#pragma unroll
    for(int ff2=0;ff2<FF;ff2++) dh1 += dzS[e*FF+ff2]*W2s[f*65+ff2];
    float z1=0.f;
#pragma unroll
    for(int b=0;b<NBB;b++) z1 += efs[e*NBB+b]*W1s[b*FF+f];
    float sg1=1.f/(1.f+__expf(-z1));
    float dz1 = dh1*sg1*(1.f+z1*(1.f-sg1));
    float def[8];
#pragma unroll
    for(int b=0;b<NBB;b++) def[b]=wred(dz1*W1s[b*FF+f]);
    size_t eg = e0+e;
    float r = cr[eg];
    float invr = 1.f/r;
    float vx=cvec[eg*3+0], vy=cvec[eg*3+1], vz=cvec[eg*3+2];
    float ux=vx*invr, uy=vy*invr, uz=vz*invr;
    float xr=r*(1.f/RMAXF);
    float x2=xr*xr, x4=x2*x2, x5=x4*xr, x6=x5*xr, x7=x6*xr;
    float env = 1.f-28.f*x6+48.f*x7-21.f*x7*xr;
    float envd = (-168.f*x5+336.f*x6-168.f*x7)*(1.f/RMAXF);
    const float CB=0.632455532f;
    float dr=0.f;
#pragma unroll
    for(int b=0;b<NBB;b++){
      float a=(b+1)*(PI_F/RMAXF);
      float ar=a*r;
      float sn_=sinf(ar), cs_=cosf(ar);
      float bess = CB*sn_*invr;
      float bessd = (ar<1e-2f) ? (-CB*a*a*a*r*(1.f/3.f))
                               : (CB*(a*cs_-sn_*invr)*invr);
      dr += def[b]*(bessd*env + bess*envd);
    }
    const float s3=1.7320508f, s5=2.23606798f, s15=3.87298335f;
    float d1=dsh[i][1],d2=dsh[i][2],d3=dsh[i][3],d4=dsh[i][4],
          d5=dsh[i][5],d6=dsh[i][6],d7=dsh[i][7],d8=dsh[i][8];
    float dux = s3*d1 + s15*(uy*d4 + uz*d7 + ux*d8);
    float duy = s3*d2 + s15*(ux*d4 + uz*d5 - uy*d8);
    float duz = s3*d3 + s15*(uy*d5 + ux*d7) + 3.f*s5*uz*d6;
    float udd = ux*dux+uy*duy+uz*duz;
    float dvx = dr*ux + (dux-ux*udd)*invr;
    float dvy = dr*uy + (duy-uy*udd)*invr;
    float dvz = dr*uz + (duz-uz*udd)*invr;
    if(f==0){
      if(LAYER==2){
        dvec[eg*3+0]=dvx; dvec[eg*3+1]=dvy; dvec[eg*3+2]=dvz;
      } else {
        int sn=sndS[e], rc=rcvS[e];
        float tx=dvec[eg*3+0]+dvx, ty=dvec[eg*3+1]+dvy, tz=dvec[eg*3+2]+dvz;
        atomicAdd(&dpos[rc*3+0], tx); atomicAdd(&dpos[rc*3+1], ty); atomicAdd(&dpos[rc*3+2], tz);
        atomicAdd(&dpos[sn*3+0],-tx); atomicAdd(&dpos[sn*3+1],-ty); atomicAdd(&dpos[sn*3+2],-tz);
      }
    }
  }
}

__global__ __launch_bounds__(256) void k_forces(const float* __restrict__ dpos,
                                                float* __restrict__ forces){
  int i = blockIdx.x*256+threadIdx.x;
  if(i < NNODES*3) forces[i] = -dpos[i];
}

extern "C" void kernel_launch(void* const* d_in, const int* in_sizes, int n_in,
                              void* d_out, int out_size, void* d_ws, size_t ws_size,
                              hipStream_t stream){
  (void)in_sizes; (void)n_in; (void)out_size; (void)ws_size;
  const float* pos    = (const float*)d_in[0];
  const float* attrs  = (const float*)d_in[1];
  const float* shifts = (const float*)d_in[2];
  const float* ae     = (const float*)d_in[3];
  const float* Wemb   = (const float*)d_in[4];
  const float* R1W1   = (const float*)d_in[5];
  const float* R1W2   = (const float*)d_in[6];
  const float* R1W3   = (const float*)d_in[7];
  const float* R1W4   = (const float*)d_in[8];
  const float* R2W1   = (const float*)d_in[9];
  const float* R2W2   = (const float*)d_in[10];
  const float* R2W3   = (const float*)d_in[11];
  const float* R2W4   = (const float*)d_in[12];
  const float* Wlin1  = (const float*)d_in[13];
  const float* Wsc1   = (const float*)d_in[14];
  const float* Wpr1   = (const float*)d_in[15];
  const float* wrd1   = (const float*)d_in[16];
  const float* Wlin2  = (const float*)d_in[17];
  const float* Wsc2   = (const float*)d_in[18];
  const float* Wpr2   = (const float*)d_in[19];
  const float* Wr1    = (const float*)d_in[20];
  const float* wr2    = (const float*)d_in[21];
  const int*   eidx   = (const int*)d_in[22];
  const int*   batch  = (const int*)d_in[23];

  float* out = (float*)d_out;
  float* ws  = (float*)d_ws;
  float* totE   = out;          // 32
  float* nodeE  = out + 32;     // 10000
  float* forces = out + 10032;  // 30000
  float* nfeats = out + 40032;  // 10000*1152

  float* h0   = ws + O_H0;
  float* s1   = ws + O_S1;
  float* agg1 = ws + O_AGG1;
  float* agg2 = ws + O_AGG2;
  float* f1   = ws + O_F1;
  float* f2   = ws + O_F2;
  float* c1   = ws + O_C1;
  float* c2   = ws + O_C2;
  float* ds1  = ws + O_DS1;
  float* csh  = ws + O_CSH;
  float* cef  = ws + O_CEF;
  float* crr  = ws + O_CR;
  float* cvec = ws + O_CVEC;
  float* dvec = ws + O_DVEC;
  float* dpos = ws + O_DPOS;
  int* csnd = (int*)(ws + O_CSND);
  int* crcv = (int*)(ws + O_CRCV);
  int* hist = (int*)(ws + O_HIST);
  int* curs = (int*)(ws + O_CURS);
  int* cnt  = (int*)(ws + O_CNT);
  float* dagg2 = agg1;
  float* dagg1 = agg2;

  hipMemsetAsync(totE, 0, 32*sizeof(float), stream);
  hipMemsetAsync(agg1, 0, (size_t)2*5760000*sizeof(float), stream); // agg1+agg2 contiguous
  hipMemsetAsync(dpos, 0, 30000*sizeof(float), stream);
  hipMemsetAsync(hist, 0, NNODES*sizeof(int), stream);

  k_embed<<<2500,256,0,stream>>>(attrs, Wemb, ae, batch, h0, totE, nodeE);
  k_count<<<1000,256,0,stream>>>(pos, shifts, eidx, hist);
  k_scan<<<1,1024,0,stream>>>(hist, curs, cnt);
  k_scatter<<<1000,256,0,stream>>>(pos, shifts, eidx, curs, csh, cef, crr, cvec, csnd, crcv);
  k_pad<<<1,32,0,stream>>>(csh, cef, crr, cvec, csnd, crcv, cnt);

  k_edge_fwd<<<ECAP/32,256,0,stream>>>(csh,cef,csnd,crcv,cnt, h0,
                                       R1W1,R1W2,R1W3,R1W4, agg1);
  k_node_fwd<1><<<2500,256,0,stream>>>(agg1, h0, batch, Wlin1, Wsc1, Wpr1,
                                       wrd1, nullptr, nullptr,
                                       f1, c1, s1, nfeats, nodeE, totE);
  k_edge_fwd<<<ECAP/32,256,0,stream>>>(csh,cef,csnd,crcv,cnt, s1,
                                       R2W1,R2W2,R2W3,R2W4, agg2);
  k_node_fwd<2><<<2500,256,0,stream>>>(agg2, s1, batch, Wlin2, Wsc2, Wpr2,
                                       nullptr, Wr1, wr2,
                                       f2, c2, nullptr, nfeats, nodeE, totE);

  k_node_bwd<2><<<2500,256,0,stream>>>(f2, c2, Wlin2, Wpr2, Wsc2, Wr1, wr2,
                                       nullptr, nullptr, nfeats, dagg2, ds1);
  k_edge_bwd<2><<<ECAP/8,256,0,stream>>>(csh,cef,crr,cvec,csnd,crcv,cnt, s1,
                                         R2W1,R2W2,R2W3,R2W4, dagg2,
                                         ds1, dvec, nullptr);
  k_node_bwd<1><<<2500,256,0,stream>>>(f1, c1, Wlin1, Wpr1, nullptr, nullptr, nullptr,
                                       wrd1, ds1, nullptr, dagg1, nullptr);
  k_edge_bwd<1><<<ECAP/8,256,0,stream>>>(csh,cef,crr,cvec,csnd,crcv,cnt, h0,
                                         R1W1,R1W2,R1W3,R1W4, dagg1,
                                         nullptr, dvec, dpos);
  k_forces<<<118,256,0,stream>>>(dpos, forces);
}

// Round 3
// 4366.239 us; speedup vs baseline: 1.9243x; 1.2919x over previous
//
#include <hip/hip_runtime.h>
#include <cstddef>

#define NNODES 10000
#define NEDGES 256000
#define NGRAPH 32
#define NELEM  10
#define FF     64
#define LL     9
#define NBB    8
#define HIDN   16
#define RMAXF  5.0f
#define INV_AVG 0.0390625f   /* 1/25.6 exact */
#define PI_F   3.14159265358979f
#define ECAP   98304         /* compact-edge capacity; expected active ~74.7k */
#define LSTR   640000        /* l-major stride for agg/dagg/feats: [l][n][f] */

// ---------------- workspace layout (float elements), ~120.5 MB ----------------
constexpr size_t O_H0    = 0;           // 640000
constexpr size_t O_S1    = 640000;      // 640000
constexpr size_t O_AGG1  = 1280000;     // 5760000 (fwd agg1; reused as d_agg2 in bwd)
constexpr size_t O_AGG2  = 7040000;     // 5760000 (fwd agg2; reused as d_agg1 in bwd)
constexpr size_t O_F1    = 12800000;    // 5760000 feats1 [l][n][g]
constexpr size_t O_F2    = 18560000;    // 5760000 feats2 [l][n][g]
constexpr size_t O_C1    = 24320000;    // 640000
constexpr size_t O_C2    = 24960000;    // 640000
constexpr size_t O_DS1   = 25600000;    // 640000
constexpr size_t O_DINV  = 26240000;    // 640000
constexpr size_t O_DH0C  = 26880000;    // 640000
constexpr size_t O_CSH   = 27520000;    // ECAP*9
constexpr size_t O_CEF   = 28404736;    // ECAP*8
constexpr size_t O_CR    = 29191168;    // ECAP
constexpr size_t O_CVEC  = 29289472;    // ECAP*3
constexpr size_t O_DVEC  = 29584384;    // ECAP*3
constexpr size_t O_DPOS  = 29879296;    // 30000
constexpr size_t O_CSND  = 29909296;    // ECAP ints
constexpr size_t O_CRCV  = 30007600;    // ECAP ints
constexpr size_t O_HIST  = 30105904;    // 10000 ints
constexpr size_t O_CURS  = 30115904;    // 10001 ints
constexpr size_t O_CNT   = 30125905;    // 2 ints

__device__ __forceinline__ float siluf(float z){
  return z*(1.f/(1.f+__expf(-z)));
}
__device__ __forceinline__ float wred(float v){
#pragma unroll
  for(int o=32;o>0;o>>=1) v += __shfl_xor(v,o,64);
  return v;
}

// ---------------- node embedding + e0 ----------------
__global__ __launch_bounds__(256) void k_embed(
    const float* __restrict__ attrs, const float* __restrict__ Wemb,
    const float* __restrict__ ae, const int* __restrict__ batch,
    float* __restrict__ h0, float* __restrict__ totE, float* __restrict__ nodeE){
  int t = blockIdx.x*256 + threadIdx.x;
  int n = t >> 6, f = t & 63;
  float acc = 0.f;
#pragma unroll
  for(int k=0;k<NELEM;k++) acc += attrs[n*NELEM+k]*Wemb[k*FF+f];
  h0[(size_t)n*FF+f] = acc;
  if(f==0){
    float e0 = 0.f;
#pragma unroll
    for(int k=0;k<NELEM;k++) e0 += attrs[n*NELEM+k]*ae[k];
    nodeE[n] = e0;
    atomicAdd(&totE[batch[n]], e0);
  }
}

// ---------------- edge sort: count / scan / scatter / pad ----------------
__global__ __launch_bounds__(256) void k_count(
    const float* __restrict__ pos, const float* __restrict__ shifts,
    const int* __restrict__ eidx, int* __restrict__ hist){
  int e = blockIdx.x*256 + threadIdx.x;
  int sn = eidx[e], rc = eidx[NEDGES + e];
  float vx = pos[rc*3+0]-pos[sn*3+0]+shifts[(size_t)e*3+0];
  float vy = pos[rc*3+1]-pos[sn*3+1]+shifts[(size_t)e*3+1];
  float vz = pos[rc*3+2]-pos[sn*3+2]+shifts[(size_t)e*3+2];
  float r2 = vx*vx+vy*vy+vz*vz+1e-12f;
  if(r2 < RMAXF*RMAXF) atomicAdd(&hist[rc], 1);
}

__global__ __launch_bounds__(1024) void k_scan(
    const int* __restrict__ hist, int* __restrict__ cursor, int* __restrict__ cnt){
  __shared__ int buf[1024];
  __shared__ int carryS;
  int t = threadIdx.x;
  if(t==0) carryS = 0;
  __syncthreads();
  for(int c=0;c<10;c++){
    int i = c*1024 + t;
    int v = (i<NNODES)? hist[i] : 0;
    buf[t]=v;
    __syncthreads();
    for(int off=1; off<1024; off<<=1){
      int x = (t>=off)? buf[t-off] : 0;
      __syncthreads();
      buf[t] += x;
      __syncthreads();
    }
    int incl = buf[t];
    int base = carryS;
    if(i<NNODES) cursor[i] = base + incl - v;
    __syncthreads();
    if(t==1023) carryS += buf[1023];
    __syncthreads();
  }
  if(t==0){
    int n = carryS;
    cnt[0] = n;
    cnt[1] = (n+31)&~31;
  }
}

__global__ __launch_bounds__(256) void k_scatter(
    const float* __restrict__ pos, const float* __restrict__ shifts, const int* __restrict__ eidx,
    int* __restrict__ cursor,
    float* __restrict__ csh, float* __restrict__ cef, float* __restrict__ cr,
    float* __restrict__ cvec, int* __restrict__ csnd, int* __restrict__ crcv){
  int e = blockIdx.x*256 + threadIdx.x;
  int sn = eidx[e], rc = eidx[NEDGES + e];
  float vx = pos[rc*3+0]-pos[sn*3+0]+shifts[(size_t)e*3+0];
  float vy = pos[rc*3+1]-pos[sn*3+1]+shifts[(size_t)e*3+1];
  float vz = pos[rc*3+2]-pos[sn*3+2]+shifts[(size_t)e*3+2];
  float r2 = vx*vx+vy*vy+vz*vz+1e-12f;
  if(r2 >= RMAXF*RMAXF) return;
  float r = sqrtf(r2);
  int i = atomicAdd(&cursor[rc], 1);
  csnd[i]=sn; crcv[i]=rc; cr[i]=r;
  cvec[(size_t)i*3+0]=vx; cvec[(size_t)i*3+1]=vy; cvec[(size_t)i*3+2]=vz;
  float inv = 1.f/r, x=vx*inv, y=vy*inv, z=vz*inv;
  const float s3=1.7320508f, s5=2.23606798f, s15=3.87298335f;
  float* sh = csh + (size_t)i*LL;
  sh[0]=1.f; sh[1]=s3*x; sh[2]=s3*y; sh[3]=s3*z; sh[4]=s15*x*y; sh[5]=s15*y*z;
  sh[6]=0.5f*s5*(3.f*z*z-1.f); sh[7]=s15*x*z; sh[8]=0.5f*s15*(x*x-y*y);
  float xr = r*(1.f/RMAXF);
  float x2=xr*xr, x4=x2*x2, x6=x4*x2, x7=x6*xr, x8=x7*xr;
  float env = 1.f - 28.f*x6 + 48.f*x7 - 21.f*x8;
  const float CB = 0.632455532f;
#pragma unroll
  for(int b=0;b<NBB;b++){
    float a = (b+1)*(PI_F/RMAXF);
    cef[(size_t)i*NBB+b] = CB*sinf(a*r)*inv*env;
  }
}

__global__ void k_pad(float* csh, float* cef, float* cr, float* cvec,
                      int* csnd, int* crcv, const int* cnt){
  int n = cnt[0];
  int nr = cnt[1];
  int i = n + threadIdx.x;
  if(i < nr){
    csnd[i]=0; crcv[i]=NNODES-1; cr[i]=1.f;
    cvec[(size_t)i*3+0]=0.f; cvec[(size_t)i*3+1]=0.f; cvec[(size_t)i*3+2]=1.f;
    for(int l=0;l<LL;l++) csh[(size_t)i*LL+l]=0.f;
    for(int b=0;b<NBB;b++) cef[(size_t)i*NBB+b]=0.f;
  }
}

// ---------------- fused edge forward: MLP -> tw -> segmented run-reduction ----------------
__global__ __launch_bounds__(256,2) void k_edge_fwd(
    const float* __restrict__ csh, const float* __restrict__ cef,
    const int* __restrict__ csnd, const int* __restrict__ crcv, const int* __restrict__ cnt,
    const float* __restrict__ src,
    const float* __restrict__ W1, const float* __restrict__ W2,
    const float* __restrict__ W3, const float* __restrict__ W4,
    float* __restrict__ agg){
  const int cnt32 = cnt[1];
  if((int)(blockIdx.x*32) >= cnt32) return;
  __shared__ float W1s[NBB*FF];
  __shared__ float W2s[FF*65], W3s[FF*65];
  __shared__ float hA[32*FF], hB[32*FF];
  __shared__ float shs[32*LL], efs[32*NBB];
  __shared__ int   sndS[32], rcvS[32];
  __shared__ float W4c[4*576];
  const int t = threadIdx.x;
  const size_t e0 = (size_t)blockIdx.x*32;
  for(int i=t;i<NBB*FF;i+=256) W1s[i]=W1[i];
  for(int i=t;i<FF*FF;i+=256){ int j=i>>6, c=i&63; W2s[j*65+c]=W2[i]; W3s[j*65+c]=W3[i]; }
  for(int i=t;i<32*LL;i+=256) shs[i]=csh[e0*LL+i];
  for(int i=t;i<32*NBB;i+=256) efs[i]=cef[e0*NBB+i];
  if(t<32){ sndS[t]=csnd[e0+t]; rcvS[t]=crcv[e0+t]; }
  __syncthreads();
  const int w=t>>6, f=t&63;
#pragma unroll
  for(int i=0;i<8;i++){
    int e=w*8+i; float z=0.f;
#pragma unroll
    for(int b=0;b<NBB;b++) z += efs[e*NBB+b]*W1s[b*FF+f];
    hA[e*FF+f]=siluf(z);
  }
  __syncthreads();
#pragma unroll
  for(int i=0;i<8;i++){
    int e=w*8+i; float z=0.f;
#pragma unroll
    for(int j=0;j<FF;j++) z += hA[e*FF+j]*W2s[j*65+f];
    hB[e*FF+f]=siluf(z);
  }
  __syncthreads();
#pragma unroll
  for(int i=0;i<8;i++){
    int e=w*8+i; float z=0.f;
#pragma unroll
    for(int j=0;j<FF;j++) z += hB[e*FF+j]*W3s[j*65+f];
    hA[e*FF+f]=siluf(z);
  }
  __syncthreads();
  float tw[8][9];
#pragma unroll
  for(int i=0;i<8;i++)
#pragma unroll
    for(int l=0;l<LL;l++) tw[i][l]=0.f;
  for(int jc=0;jc<16;jc++){
    for(int i=t;i<4*576;i+=256) W4c[i]=W4[jc*(4*576)+i];
    __syncthreads();
#pragma unroll
    for(int j4=0;j4<4;j4++){
      int j=jc*4+j4;
      float wv[9];
#pragma unroll
      for(int l=0;l<LL;l++) wv[l]=W4c[j4*576 + f*LL + l];
#pragma unroll
      for(int i=0;i<8;i++){
        float h3 = hA[(w*8+i)*FF + j];
#pragma unroll
        for(int l=0;l<LL;l++) tw[i][l] += h3*wv[l];
      }
    }
    __syncthreads();
  }
  // epilogue: per-l LDS run reduction into l-major agg [l][n][f]
  float sv[8];
#pragma unroll
  for(int i=0;i<8;i++) sv[i] = src[(size_t)sndS[w*8+i]*FF + f];
  const bool leftStraddle  = (e0>0) && (crcv[e0-1] == rcvS[0]);
  const bool rightStraddle = ((int)(e0+32) < cnt32) && (crcv[e0+32] == rcvS[31]);
  float* msgL = hA;
#pragma unroll
  for(int l=0;l<LL;l++){
#pragma unroll
    for(int i=0;i<8;i++){
      int e=w*8+i;
      msgL[e*FF+f] = sv[i]*shs[e*LL+l]*tw[i][l]*INV_AVG;
    }
    __syncthreads();
#pragma unroll
    for(int s0=0;s0<8;s0++){
      int s = w*8+s0;
      int rc = rcvS[s];
      bool head = (s==0) || (rcvS[s-1]!=rc);
      if(head){
        int L=1;
        while(s+L<32 && rcvS[s+L]==rc) L++;
        float sum=0.f;
        for(int k=0;k<L;k++) sum += msgL[(s+k)*FF+f];
        bool atom = (s==0 && leftStraddle) || (s+L==32 && rightStraddle);
        float* ap = &agg[(size_t)l*LSTR + (size_t)rc*FF + f];
        if(atom) atomicAdd(ap, sum); else *ap = sum;
      }
    }
    __syncthreads();
  }
}

// ---------------- k_lin: feats[l][n][g] = sum_f agg[l][n][f]*Wlin[l][f][g] (+sc at l=0) ----
__global__ __launch_bounds__(256,2) void k_lin(
    const float* __restrict__ agg, const float* __restrict__ Wlin,
    const float* __restrict__ src, const float* __restrict__ Wsc,
    float* __restrict__ feats){
  const int l  = blockIdx.y;
  const int n0 = blockIdx.x*64;
  __shared__ float Wl[FF*65];
  __shared__ float aggS[64*FF];
  const int t=threadIdx.x, w=t>>6, g=t&63;
  for(int i=t;i<FF*FF;i+=256) Wl[(i>>6)*65+(i&63)] = Wlin[(size_t)l*FF*FF+i];
  for(int i=t;i<64*FF;i+=256){
    int n = n0 + (i>>6);
    aggS[i] = (n<NNODES)? agg[(size_t)l*LSTR + (size_t)n*FF + (i&63)] : 0.f;
  }
  __syncthreads();
  float acc[16];
#pragma unroll
  for(int i=0;i<16;i++) acc[i]=0.f;
  auto mac = [&](){
#pragma unroll
    for(int r=0;r<4;r++){
      int nb=(w*16+r*4)*FF;
      float a0=acc[r*4+0],a1=acc[r*4+1],a2=acc[r*4+2],a3=acc[r*4+3];
#pragma unroll
      for(int f4=0;f4<16;f4++){
        float w0=Wl[(f4*4+0)*65+g], w1=Wl[(f4*4+1)*65+g],
              w2=Wl[(f4*4+2)*65+g], w3=Wl[(f4*4+3)*65+g];
        const float4 v0 = *(const float4*)&aggS[nb + 0*FF + f4*4];
        const float4 v1 = *(const float4*)&aggS[nb + 1*FF + f4*4];
        const float4 v2 = *(const float4*)&aggS[nb + 2*FF + f4*4];
        const float4 v3 = *(const float4*)&aggS[nb + 3*FF + f4*4];
        a0 += w0*v0.x+w1*v0.y+w2*v0.z+w3*v0.w;
        a1 += w0*v1.x+w1*v1.y+w2*v1.z+w3*v1.w;
        a2 += w0*v2.x+w1*v2.y+w2*v2.z+w3*v2.w;
        a3 += w0*v3.x+w1*v3.y+w2*v3.z+w3*v3.w;
      }
      acc[r*4+0]=a0; acc[r*4+1]=a1; acc[r*4+2]=a2; acc[r*4+3]=a3;
    }
  };
  mac();
  if(l==0){
    __syncthreads();
    for(int i=t;i<FF*FF;i+=256) Wl[(i>>6)*65+(i&63)] = Wsc[i];
    for(int i=t;i<64*FF;i+=256){
      int n = n0 + (i>>6);
      aggS[i] = (n<NNODES)? src[(size_t)n*FF + (i&63)] : 0.f;
    }
    __syncthreads();
    mac();
  }
#pragma unroll
  for(int i=0;i<16;i++){
    int n = n0 + w*16 + i;
    if(n<NNODES) feats[(size_t)l*LSTR + (size_t)n*FF + g] = acc[i];
  }
}

// ---------------- k_prod: inv, c, h, readout energies ----------------
template<int LAYER>
__global__ __launch_bounds__(256,2) void k_prod(
    const float* __restrict__ feats, const int* __restrict__ batch,
    const float* __restrict__ Wpr,
    const float* __restrict__ wread, const float* __restrict__ Wr1, const float* __restrict__ wr2,
    float* __restrict__ cbuf, float* __restrict__ s1out,
    float* __restrict__ nfeats, float* __restrict__ nodeE, float* __restrict__ totE){
  __shared__ float Wprs[FF*65];
  __shared__ float Wr1s[FF*HIDN];
  __shared__ float ivS[4][FF];
  const int t=threadIdx.x, w=t>>6, g=t&63;
  for(int i=t;i<FF*FF;i+=256) Wprs[(i>>6)*65+(i&63)]=Wpr[i];
  if(LAYER==2) for(int i=t;i<FF*HIDN;i+=256) Wr1s[i]=Wr1[i];
  __syncthreads();
  for(int k=0;k<8;k++){
    int n = blockIdx.x*32 + k*4 + w;
    if(n>=NNODES) continue;   // wave-uniform; no block barriers below
    float fr[9]; float iv=0.f;
#pragma unroll
    for(int l=0;l<LL;l++){ fr[l]=feats[(size_t)l*LSTR + (size_t)n*FF + g]; iv+=fr[l]*fr[l]; }
    ivS[w][g]=iv;
    float c=1.f;
#pragma unroll
    for(int gg=0;gg<FF;gg++) c += ivS[w][gg]*Wprs[gg*65+g];
    cbuf[(size_t)n*FF+g]=c;
    float* nf = nfeats + (size_t)n*(2*FF*LL) + (LAYER==2?FF*LL:0) + g*LL;
#pragma unroll
    for(int l=0;l<LL;l++) nf[l]=fr[l]*c;
    float s0 = fr[0]*c;
    float epart;
    if(LAYER==1){
      s1out[(size_t)n*FF+g]=s0;
      epart = s0*wread[g];
    } else {
      ivS[w][g]=s0;
      epart=0.f;
      if(g<HIDN){
        float tt=0.f;
#pragma unroll
        for(int gg=0;gg<FF;gg++) tt += ivS[w][gg]*Wr1s[gg*HIDN+g];
        epart = siluf(tt)*wr2[g];
      }
    }
    float es = wred(epart);
    if(g==0){ nodeE[n]+=es; atomicAdd(&totE[batch[n]], es); }
  }
}

// ---------------- k_bwd_prep: dh0 -> dinv, dh0*c, (L2) ds1 ----------------
template<int LAYER>
__global__ __launch_bounds__(256,2) void k_bwd_prep(
    const float* __restrict__ feats, const float* __restrict__ cbuf,
    const float* __restrict__ Wpr, const float* __restrict__ Wsc,
    const float* __restrict__ Wr1, const float* __restrict__ wr2,
    const float* __restrict__ wread, const float* __restrict__ ds1in,
    float* __restrict__ dinvb, float* __restrict__ dh0cb,
    float* __restrict__ ds1out){
  __shared__ float Wprs[FF*65];
  __shared__ float Wscs[FF*65];
  __shared__ float Wr1s[FF*HIDN];
  __shared__ float Wr1T[HIDN*FF];
  __shared__ float rowS[4][FF];
  __shared__ float dtS[4][HIDN];
  const int t=threadIdx.x, w=t>>6, g=t&63;
  for(int i=t;i<FF*FF;i+=256) Wprs[(i>>6)*65+(i&63)]=Wpr[i];
  if(LAYER==2){
    for(int i=t;i<FF*FF;i+=256) Wscs[(i>>6)*65+(i&63)]=Wsc[i];
    for(int i=t;i<FF*HIDN;i+=256){
      Wr1s[i]=Wr1[i];
      Wr1T[(i&15)*FF + (i>>4)] = Wr1[i];
    }
  }
  __syncthreads();
  for(int k=0;k<8;k++){
    int n = blockIdx.x*32 + k*4 + w;
    if(n>=NNODES) continue;
    float f0 = feats[(size_t)n*FF+g];        // l=0 plane
    float c  = cbuf[(size_t)n*FF+g];
    float dh0;
    if(LAYER==2){
      rowS[w][g] = f0*c;                     // s2 row
      if(g<HIDN){
        float tt=0.f;
#pragma unroll
        for(int gg=0;gg<FF;gg++) tt += rowS[w][gg]*Wr1s[gg*HIDN+g];
        float sg = 1.f/(1.f+__expf(-tt));
        dtS[w][g] = sg*(1.f + tt*(1.f-sg))*wr2[g];
      }
      dh0=0.f;
#pragma unroll
      for(int h=0;h<HIDN;h++) dh0 += dtS[w][h]*Wr1T[h*FF+g];
    } else {
      dh0 = wread[g] + ds1in[(size_t)n*FF+g];
    }
    rowS[w][g] = dh0*f0;                     // dc
    float dinv=0.f;
#pragma unroll
    for(int gg=0;gg<FF;gg++) dinv += rowS[w][gg]*Wprs[g*65+gg];
    dinvb[(size_t)n*FF+g]=dinv;
    dh0cb[(size_t)n*FF+g]=dh0*c;
    if(LAYER==2){
      rowS[w][g] = 2.f*dinv*f0 + dh0*c;      // df0
      float ds=0.f;
#pragma unroll
      for(int gg=0;gg<FF;gg++) ds += rowS[w][gg]*Wscs[g*65+gg];
      ds1out[(size_t)n*FF+g]=ds;
    }
  }
}

// ---------------- k_lin_bwd: dagg[l][n][f] = sum_g df[l][n][g]*Wlin[l][f][g] ----------------
__global__ __launch_bounds__(256,2) void k_lin_bwd(
    const float* __restrict__ feats, const float* __restrict__ Wlin,
    const float* __restrict__ dinvb, const float* __restrict__ dh0cb,
    float* __restrict__ dagg){
  const int l  = blockIdx.y;
  const int n0 = blockIdx.x*64;
  __shared__ float Wl[FF*65];
  __shared__ float dfS[64*FF];
  const int t=threadIdx.x, w=t>>6, f=t&63;
  for(int i=t;i<FF*FF;i+=256) Wl[(i>>6)*65+(i&63)]=Wlin[(size_t)l*FF*FF+i];
  for(int i=t;i<64*FF;i+=256){
    int n=n0+(i>>6); int g=i&63;
    float v=0.f;
    if(n<NNODES){
      float ft = feats[(size_t)l*LSTR+(size_t)n*FF+g];
      v = 2.f*dinvb[(size_t)n*FF+g]*ft;
      if(l==0) v += dh0cb[(size_t)n*FF+g];
    }
    dfS[i]=v;
  }
  __syncthreads();
  float acc[16];
#pragma unroll
  for(int i=0;i<16;i++) acc[i]=0.f;
#pragma unroll
  for(int r=0;r<4;r++){
    int nb=(w*16+r*4)*FF;
    float a0=0,a1=0,a2=0,a3=0;
#pragma unroll
    for(int g4=0;g4<16;g4++){
      float w0=Wl[f*65+g4*4+0], w1=Wl[f*65+g4*4+1],
            w2=Wl[f*65+g4*4+2], w3=Wl[f*65+g4*4+3];
      const float4 v0 = *(const float4*)&dfS[nb + 0*FF + g4*4];
      const float4 v1 = *(const float4*)&dfS[nb + 1*FF + g4*4];
      const float4 v2 = *(const float4*)&dfS[nb + 2*FF + g4*4];
      const float4 v3 = *(const float4*)&dfS[nb + 3*FF + g4*4];
      a0 += w0*v0.x+w1*v0.y+w2*v0.z+w3*v0.w;
      a1 += w0*v1.x+w1*v1.y+w2*v1.z+w3*v1.w;
      a2 += w0*v2.x+w1*v2.y+w2*v2.z+w3*v2.w;
      a3 += w0*v3.x+w1*v3.y+w2*v3.z+w3*v3.w;
    }
    acc[r*4+0]=a0; acc[r*4+1]=a1; acc[r*4+2]=a2; acc[r*4+3]=a3;
  }
#pragma unroll
  for(int i=0;i<16;i++){
    int n = n0 + w*16 + i;
    if(n<NNODES) dagg[(size_t)l*LSTR + (size_t)n*FF + f] = acc[i];
  }
}

// ---------------- fused edge backward (single W4 pass, l-major dagg) ----------------
template<int LAYER>
__global__ __launch_bounds__(256,2) void k_edge_bwd(
    const float* __restrict__ csh, const float* __restrict__ cef,
    const float* __restrict__ cr, const float* __restrict__ cvec,
    const int* __restrict__ csnd, const int* __restrict__ crcv, const int* __restrict__ cnt,
    const float* __restrict__ src,
    const float* __restrict__ W1, const float* __restrict__ W2,
    const float* __restrict__ W3, const float* __restrict__ W4,
    const float* __restrict__ dagg,
    float* __restrict__ ds1,
    float* __restrict__ dvec,
    float* __restrict__ dpos){
  if((int)(blockIdx.x*8) >= cnt[1]) return;
  __shared__ float W1s[NBB*FF];
  __shared__ float W2s[FF*65], W3s[FF*65];
  __shared__ float h1S[8*FF], h2S[8*FF], h3S[8*FF];
  __shared__ float shs[8*LL], efs[8*NBB];
  __shared__ int sndS[8], rcvS[8];
  __shared__ float W4c[4*576];
  __shared__ float redS[4*8*FF];
  __shared__ float redS2[32*8];
  __shared__ float dh3S[8*FF];
  __shared__ float dzS[8*FF];
  const int t=threadIdx.x, w=t>>6, f=t&63;
  const size_t e0=(size_t)blockIdx.x*8;
  for(int i=t;i<NBB*FF;i+=256) W1s[i]=W1[i];
  for(int i=t;i<FF*FF;i+=256){ int j=i>>6,c=i&63; W2s[j*65+c]=W2[i]; W3s[j*65+c]=W3[i]; }
  for(int i=t;i<8*LL;i+=256) shs[i]=csh[e0*LL+i];
  for(int i=t;i<8*NBB;i+=256) efs[i]=cef[e0*NBB+i];
  if(t<8){ sndS[t]=csnd[e0+t]; rcvS[t]=crcv[e0+t]; }
  __syncthreads();
#pragma unroll
  for(int i=0;i<2;i++){
    int e=w*2+i; float z=0.f;
#pragma unroll
    for(int b=0;b<NBB;b++) z += efs[e*NBB+b]*W1s[b*FF+f];
    h1S[e*FF+f]=siluf(z);
  }
  __syncthreads();
#pragma unroll
  for(int i=0;i<2;i++){
    int e=w*2+i; float z=0.f;
#pragma unroll
    for(int j=0;j<FF;j++) z += h1S[e*FF+j]*W2s[j*65+f];
    h2S[e*FF+f]=siluf(z);
  }
  __syncthreads();
#pragma unroll
  for(int i=0;i<2;i++){
    int e=w*2+i; float z=0.f;
#pragma unroll
    for(int j=0;j<FF;j++) z += h2S[e*FF+j]*W3s[j*65+f];
    h3S[e*FF+f]=siluf(z);
  }
  __syncthreads();
  // dm in registers (l-major dagg: contiguous 256B wave loads per l)
  float dm[2][9], dtw[2][9], sv[2];
#pragma unroll
  for(int i=0;i<2;i++){
    int e=w*2+i;
    int sn=sndS[e], rc=rcvS[e];
    sv[i] = src[(size_t)sn*FF+f];
#pragma unroll
    for(int l=0;l<LL;l++){
      dm[i][l] = dagg[(size_t)l*LSTR + (size_t)rc*FF + f]*INV_AVG;
      dtw[i][l] = dm[i][l]*sv[i]*shs[e*LL+l];
    }
  }
  // single W4 pass: tw accumulate + dh3 partials
  float tw[2][9];
#pragma unroll
  for(int i=0;i<2;i++)
#pragma unroll
    for(int l=0;l<LL;l++) tw[i][l]=0.f;
  for(int jc=0;jc<16;jc++){
    for(int i2=t;i2<4*576;i2+=256) W4c[i2]=W4[jc*(4*576)+i2];
    __syncthreads();
#pragma unroll
    for(int j4=0;j4<4;j4++){
      int j=jc*4+j4;
      float wv[9];
#pragma unroll
      for(int l=0;l<LL;l++) wv[l]=W4c[j4*576+f*LL+l];
#pragma unroll
      for(int i=0;i<2;i++){
        float h3=h3S[(w*2+i)*FF+j];
        float p=0.f;
#pragma unroll
        for(int l=0;l<LL;l++){ tw[i][l]+=h3*wv[l]; p += dtw[i][l]*wv[l]; }
        redS[(j4*8 + (w*2+i))*FF + f] = p;
      }
    }
    __syncthreads();
    {
      int row=t>>3, seg=t&7;
      float s=0.f;
#pragma unroll
      for(int k=0;k<8;k++) s += redS[row*FF + seg*8 + k];
      redS2[t]=s;
    }
    __syncthreads();
    if(t<32){
      float s=0.f;
#pragma unroll
      for(int k=0;k<8;k++) s += redS2[t*8+k];
      int j4=t>>3, e=t&7;
      dh3S[e*FF + jc*4 + j4] = s;
    }
    __syncthreads();
  }
  // dsh, ds1 — need tw
  float dsh[2][9];
#pragma unroll
  for(int i=0;i<2;i++){
    int e=w*2+i;
    int sn=sndS[e];
    if(LAYER==2){
      float A=0.f;
#pragma unroll
      for(int l=0;l<LL;l++) A += dm[i][l]*shs[e*LL+l]*tw[i][l];
      atomicAdd(&ds1[(size_t)sn*FF+f], A);
    }
#pragma unroll
    for(int l=0;l<LL;l++) dsh[i][l] = wred(dm[i][l]*sv[i]*tw[i][l]);
  }
  // MLP chain backprop + geometry
#pragma unroll
  for(int i=0;i<2;i++){
    int e=w*2+i;
    float z3=0.f;
#pragma unroll
    for(int j=0;j<FF;j++) z3 += h2S[e*FF+j]*W3s[j*65+f];
    float sg3 = 1.f/(1.f+__expf(-z3));
    float dz3 = dh3S[e*FF+f]*sg3*(1.f + z3*(1.f-sg3));
    __syncthreads();
    dzS[e*FF+f]=dz3;
    __syncthreads();
    float dh2=0.f;
#pragma unroll
    for(int ff2=0;ff2<FF;ff2++) dh2 += dzS[e*FF+ff2]*W3s[f*65+ff2];
    float z2=0.f;
#pragma unroll
    for(int j=0;j<FF;j++) z2 += h1S[e*FF+j]*W2s[j*65+f];
    float sg2=1.f/(1.f+__expf(-z2));
    float dz2 = dh2*sg2*(1.f+z2*(1.f-sg2));
    __syncthreads();
    dzS[e*FF+f]=dz2;
    __syncthreads();
    float dh1=0.f;
#pragma unroll
    for(int ff2=0;ff2<FF;ff2++) dh1 += dzS[e*FF+ff2]*W2s[f*65+ff2];
    float z1=0.f;
#pragma unroll
    for(int b=0;b<NBB;b++) z1 += efs[e*NBB+b]*W1s[b*FF+f];
    float sg1=1.f/(1.f+__expf(-z1));
    float dz1 = dh1*sg1*(1.f+z1*(1.f-sg1));
    float def[8];
#pragma unroll
    for(int b=0;b<NBB;b++) def[b]=wred(dz1*W1s[b*FF+f]);
    size_t eg = e0+e;
    float r = cr[eg];
    float invr = 1.f/r;
    float vx=cvec[eg*3+0], vy=cvec[eg*3+1], vz=cvec[eg*3+2];
    float ux=vx*invr, uy=vy*invr, uz=vz*invr;
    float xr=r*(1.f/RMAXF);
    float x2=xr*xr, x4=x2*x2, x5=x4*xr, x6=x5*xr, x7=x6*xr;
    float env = 1.f-28.f*x6+48.f*x7-21.f*x7*xr;
    float envd = (-168.f*x5+336.f*x6-168.f*x7)*(1.f/RMAXF);
    const float CB=0.632455532f;
    float dr=0.f;
#pragma unroll
    for(int b=0;b<NBB;b++){
      float a=(b+1)*(PI_F/RMAXF);
      float ar=a*r;
      float sn_=sinf(ar), cs_=cosf(ar);
      float bess = CB*sn_*invr;
      float bessd = (ar<1e-2f) ? (-CB*a*a*a*r*(1.f/3.f))
                               : (CB*(a*cs_-sn_*invr)*invr);
      dr += def[b]*(bessd*env + bess*envd);
    }
    const float s3=1.7320508f, s5=2.23606798f, s15=3.87298335f;
    float d1=dsh[i][1],d2=dsh[i][2],d3=dsh[i][3],d4=dsh[i][4],
          d5=dsh[i][5],d6=dsh[i][6],d7=dsh[i][7],d8=dsh[i][8];
    float dux = s3*d1 + s15*(uy*d4 + uz*d7 + ux*d8);
    float duy = s3*d2 + s15*(ux*d4 + uz*d5 - uy*d8);
    float duz = s3*d3 + s15*(uy*d5 + ux*d7) + 3.f*s5*uz*d6;
    float udd = ux*dux+uy*duy+uz*duz;
    float dvx = dr*ux + (dux-ux*udd)*invr;
    float dvy = dr*uy + (duy-uy*udd)*invr;
    float dvz = dr*uz + (duz-uz*udd)*invr;
    if(f==0){
      if(LAYER==2){
        dvec[eg*3+0]=dvx; dvec[eg*3+1]=dvy; dvec[eg*3+2]=dvz;
      } else {
        int sn=sndS[e], rc=rcvS[e];
        float tx=dvec[eg*3+0]+dvx, ty=dvec[eg*3+1]+dvy, tz=dvec[eg*3+2]+dvz;
        atomicAdd(&dpos[rc*3+0], tx); atomicAdd(&dpos[rc*3+1], ty); atomicAdd(&dpos[rc*3+2], tz);
        atomicAdd(&dpos[sn*3+0],-tx); atomicAdd(&dpos[sn*3+1],-ty); atomicAdd(&dpos[sn*3+2],-tz);
      }
    }
  }
}

__global__ __launch_bounds__(256) void k_forces(const float* __restrict__ dpos,
                                                float* __restrict__ forces){
  int i = blockIdx.x*256+threadIdx.x;
  if(i < NNODES*3) forces[i] = -dpos[i];
}

extern "C" void kernel_launch(void* const* d_in, const int* in_sizes, int n_in,
                              void* d_out, int out_size, void* d_ws, size_t ws_size,
                              hipStream_t stream){
  (void)in_sizes; (void)n_in; (void)out_size; (void)ws_size;
  const float* pos    = (const float*)d_in[0];
  const float* attrs  = (const float*)d_in[1];
  const float* shifts = (const float*)d_in[2];
  const float* ae     = (const float*)d_in[3];
  const float* Wemb   = (const float*)d_in[4];
  const float* R1W1   = (const float*)d_in[5];
  const float* R1W2   = (const float*)d_in[6];
  const float* R1W3   = (const float*)d_in[7];
  const float* R1W4   = (const float*)d_in[8];
  const float* R2W1   = (const float*)d_in[9];
  const float* R2W2   = (const float*)d_in[10];
  const float* R2W3   = (const float*)d_in[11];
  const float* R2W4   = (const float*)d_in[12];
  const float* Wlin1  = (const float*)d_in[13];
  const float* Wsc1   = (const float*)d_in[14];
  const float* Wpr1   = (const float*)d_in[15];
  const float* wrd1   = (const float*)d_in[16];
  const float* Wlin2  = (const float*)d_in[17];
  const float* Wsc2   = (const float*)d_in[18];
  const float* Wpr2   = (const float*)d_in[19];
  const float* Wr1    = (const float*)d_in[20];
  const float* wr2    = (const float*)d_in[21];
  const int*   eidx   = (const int*)d_in[22];
  const int*   batch  = (const int*)d_in[23];

  float* out = (float*)d_out;
  float* ws  = (float*)d_ws;
  float* totE   = out;          // 32
  float* nodeE  = out + 32;     // 10000
  float* forces = out + 10032;  // 30000
  float* nfeats = out + 40032;  // 10000*1152

  float* h0   = ws + O_H0;
  float* s1   = ws + O_S1;
  float* agg1 = ws + O_AGG1;
  float* agg2 = ws + O_AGG2;
  float* f1   = ws + O_F1;
  float* f2   = ws + O_F2;
  float* c1   = ws + O_C1;
  float* c2   = ws + O_C2;
  float* ds1  = ws + O_DS1;
  float* dinv = ws + O_DINV;
  float* dh0c = ws + O_DH0C;
  float* csh  = ws + O_CSH;
  float* cef  = ws + O_CEF;
  float* crr  = ws + O_CR;
  float* cvec = ws + O_CVEC;
  float* dvec = ws + O_DVEC;
  float* dpos = ws + O_DPOS;
  int* csnd = (int*)(ws + O_CSND);
  int* crcv = (int*)(ws + O_CRCV);
  int* hist = (int*)(ws + O_HIST);
  int* curs = (int*)(ws + O_CURS);
  int* cnt  = (int*)(ws + O_CNT);
  float* dagg2 = agg1;
  float* dagg1 = agg2;

  hipMemsetAsync(totE, 0, 32*sizeof(float), stream);
  hipMemsetAsync(agg1, 0, (size_t)2*5760000*sizeof(float), stream);
  hipMemsetAsync(dpos, 0, 30000*sizeof(float), stream);
  hipMemsetAsync(hist, 0, NNODES*sizeof(int), stream);

  dim3 gLin(157,9);

  k_embed<<<2500,256,0,stream>>>(attrs, Wemb, ae, batch, h0, totE, nodeE);
  k_count<<<1000,256,0,stream>>>(pos, shifts, eidx, hist);
  k_scan<<<1,1024,0,stream>>>(hist, curs, cnt);
  k_scatter<<<1000,256,0,stream>>>(pos, shifts, eidx, curs, csh, cef, crr, cvec, csnd, crcv);
  k_pad<<<1,32,0,stream>>>(csh, cef, crr, cvec, csnd, crcv, cnt);

  k_edge_fwd<<<ECAP/32,256,0,stream>>>(csh,cef,csnd,crcv,cnt, h0,
                                       R1W1,R1W2,R1W3,R1W4, agg1);
  k_lin<<<gLin,256,0,stream>>>(agg1, Wlin1, h0, Wsc1, f1);
  k_prod<1><<<313,256,0,stream>>>(f1, batch, Wpr1, wrd1, nullptr, nullptr,
                                  c1, s1, nfeats, nodeE, totE);
  k_edge_fwd<<<ECAP/32,256,0,stream>>>(csh,cef,csnd,crcv,cnt, s1,
                                       R2W1,R2W2,R2W3,R2W4, agg2);
  k_lin<<<gLin,256,0,stream>>>(agg2, Wlin2, s1, Wsc2, f2);
  k_prod<2><<<313,256,0,stream>>>(f2, batch, Wpr2, nullptr, Wr1, wr2,
                                  c2, nullptr, nfeats, nodeE, totE);

  k_bwd_prep<2><<<313,256,0,stream>>>(f2, c2, Wpr2, Wsc2, Wr1, wr2,
                                      nullptr, nullptr, dinv, dh0c, ds1);
  k_lin_bwd<<<gLin,256,0,stream>>>(f2, Wlin2, dinv, dh0c, dagg2);
  k_edge_bwd<2><<<ECAP/8,256,0,stream>>>(csh,cef,crr,cvec,csnd,crcv,cnt, s1,
                                         R2W1,R2W2,R2W3,R2W4, dagg2,
                                         ds1, dvec, nullptr);
  k_bwd_prep<1><<<313,256,0,stream>>>(f1, c1, Wpr1, nullptr, nullptr, nullptr,
                                      wrd1, ds1, dinv, dh0c, nullptr);
  k_lin_bwd<<<gLin,256,0,stream>>>(f1, Wlin1, dinv, dh0c, dagg1);
  k_edge_bwd<1><<<ECAP/8,256,0,stream>>>(csh,cef,crr,cvec,csnd,crcv,cnt, h0,
                                         R1W1,R1W2,R1W3,R1W4, dagg1,
                                         nullptr, dvec, dpos);
  k_forces<<<118,256,0,stream>>>(dpos, forces);
}